// Round 11
// baseline (585.646 us; speedup 1.0000x reference)
//
#include <hip/hip_runtime.h>

#define NN 100000
#define NE 1600000
#define HH 32
#define CC 10
#define GG 64
#define STRIP 25000
#define NB 391        // node buckets of 256 (391*256 = 100096 >= NN)
#define PBLK 100      // edge-pass blocks
#define ECH 16000     // edges per pass block (100*16000 = NE)
#define MTOT (NB * PBLK)

typedef _Float16 half8 __attribute__((ext_vector_type(8)));
typedef _Float16 half2v __attribute__((ext_vector_type(2)));
typedef float f32x4 __attribute__((ext_vector_type(4)));

// ---------------- workspace layout ----------------
// float4 xpad[NN]; uint agg[STRIP*320]; int csr_row[NE]; uint part[NE];
// int mat[MTOT], ideg[NN], offs[NN+1]; float dinv[NN], tab[16384];
// _Float16 Mfrag[20480]; _Float16 xh1[NN*32]; float U[NN*32]; _Float16 Vh[NN*32];
// float h2[NN*32], pooled, counts

__global__ void zero_f(float* p, int n) {
    int i = blockIdx.x * 256 + threadIdx.x;
    if (i < n) p[i] = 0.0f;
}

__global__ void precompute_small(const float* __restrict__ fW, const float* __restrict__ fb,
                                 const float* __restrict__ W1, const float* __restrict__ b1,
                                 const float* __restrict__ W2, const float* __restrict__ b2,
                                 const float* __restrict__ g1W, float* __restrict__ tab) {
    int c = blockIdx.x;
    int k = threadIdx.x >> 5;
    int j = threadIdx.x & 31;
    float m = 0.f;
    for (int mm = 0; mm < 32; ++mm)
        m += W2[k * 32 + mm] * g1W[(3 + 32 * c + mm) * 32 + j];
    tab[2240 + c * 1024 + k * 32 + j] = m;

    if (k < 3) {
        float a = 0.f, b = 0.f;
        for (int i = 0; i < 32; ++i) {
            float w = fW[c * 96 + k * 32 + i];
            a += w * W1[i * 32 + j];
            b += w * W1[(32 + i) * 32 + j];
        }
        tab[c * 96 + k * 32 + j] = a;
        tab[960 + c * 96 + k * 32 + j] = b;
    } else if (k == 3) {
        float h = b1[j];
        for (int i = 0; i < 32; ++i)
            h += fb[c * 32 + i] * (W1[i * 32 + j] + W1[(32 + i) * 32 + j]);
        tab[1920 + c * 32 + j] = h;
    } else if (k == 4 && c == 0) {
        float t = 0.f;
        for (int cc2 = 0; cc2 < CC; ++cc2)
            for (int mm = 0; mm < 32; ++mm)
                t += b2[mm] * g1W[(3 + 32 * cc2 + mm) * 32 + j];
        tab[12480 + j] = t;
    }
}

// Pre-swizzle Mflat[320][32] into MFMA B-fragment order, fp16 hi/lo planes.
__global__ void mfrag_kernel(const float* __restrict__ tab, _Float16* __restrict__ Mfrag) {
    int gid = blockIdx.x * 256 + threadIdx.x;   // [0, 2560)
    if (gid >= 2560) return;
    int set = gid >> 6, l = gid & 63;
    int p = set & 1, jt = (set >> 1) & 1, kc = set >> 2;
    int j = jt * 16 + (l & 15);
    int kbase = kc * 32 + (l >> 4) * 8;
#pragma unroll
    for (int i = 0; i < 8; ++i) {
        float v = tab[2240 + (kbase + i) * 32 + j];
        _Float16 hi = (_Float16)v;
        Mfrag[gid * 8 + i] = p ? (_Float16)(v - (float)hi) : hi;
    }
}

// ---- atomic-free CSR build: bucketed counting sort (LDS atomics only) ----
// P1: per-block LDS histogram over NB buckets (bucket = col >> 8)
__global__ void bucket_hist(const int* __restrict__ ei, int* __restrict__ mat) {
    __shared__ int h[NB];
    int blk = blockIdx.x, tid = threadIdx.x;
    for (int i = tid; i < NB; i += 256) h[i] = 0;
    __syncthreads();
    int base = blk * ECH;
    for (int k = tid; k < ECH; k += 256)
        atomicAdd(&h[ei[NE + base + k] >> 8], 1);
    __syncthreads();
    for (int i = tid; i < NB; i += 256) mat[i * PBLK + blk] = h[i];
}

// P2: exclusive scan of mat (bucket-major, block-minor), in place; single block
__global__ void scan_mat(int* __restrict__ mat) {
    __shared__ int sums[1024];
    int t = threadIdx.x;
    const int CH = (MTOT + 1023) / 1024;   // 39
    int base = t * CH;
    int s = 0;
    for (int i = 0; i < CH; ++i) { int idx = base + i; if (idx < MTOT) s += mat[idx]; }
    sums[t] = s;
    __syncthreads();
    for (int off = 1; off < 1024; off <<= 1) {
        int v = (t >= off) ? sums[t - off] : 0;
        __syncthreads();
        sums[t] += v;
        __syncthreads();
    }
    int run = (t == 0) ? 0 : sums[t - 1];
    for (int i = 0; i < CH; ++i) {
        int idx = base + i;
        if (idx < MTOT) { int v = mat[idx]; mat[idx] = run; run += v; }
    }
}

// P3: scatter edges into bucket-partitioned part[]; packed r | (c_local<<24)
__global__ void bucket_scatter(const int* __restrict__ ei, const int* __restrict__ mat,
                               unsigned int* __restrict__ part) {
    __shared__ int bas[NB];
    __shared__ int cur[NB];
    int blk = blockIdx.x, tid = threadIdx.x;
    for (int i = tid; i < NB; i += 256) { bas[i] = mat[i * PBLK + blk]; cur[i] = 0; }
    __syncthreads();
    int base = blk * ECH;
    for (int k = tid; k < ECH; k += 256) {
        int e = base + k;
        int r = ei[e];
        int c = ei[NE + e];
        int b = c >> 8;
        int local = atomicAdd(&cur[b], 1);
        part[bas[b] + local] = (unsigned)r | ((unsigned)(c & 255) << 24);
    }
}

// P4: per-bucket (256 nodes) histogram+scan in LDS; writes ideg/offs/dinv/xpad
// coalesced and csr_row grouped by node. No global atomics.
__global__ void bucket_build(const unsigned int* __restrict__ part, const int* __restrict__ mat,
                             const float* __restrict__ x, int* __restrict__ csr_row,
                             int* __restrict__ ideg, int* __restrict__ offs,
                             float* __restrict__ dinv, float4* __restrict__ xpad) {
    __shared__ int lh[256];
    __shared__ int lex[256];
    __shared__ int cur[256];
    int b = blockIdx.x, tid = threadIdx.x;
    int ebase = mat[b * PBLK];
    int eend = (b == NB - 1) ? NE : mat[(b + 1) * PBLK];
    int m = eend - ebase;
    lh[tid] = 0;
    __syncthreads();
    for (int k = tid; k < m; k += 256) {
        unsigned v = part[ebase + k];
        atomicAdd(&lh[v >> 24], 1);
    }
    __syncthreads();
    int cnt = lh[tid];
    lex[tid] = cnt;
    __syncthreads();
    for (int off = 1; off < 256; off <<= 1) {
        int v = (tid >= off) ? lex[tid - off] : 0;
        __syncthreads();
        lex[tid] += v;
        __syncthreads();
    }
    int excl = lex[tid] - cnt;
    lex[tid] = excl;            // own-slot rewrite; synced below before random reads
    cur[tid] = 0;
    int n = b * 256 + tid;
    if (n < NN) {
        ideg[n] = cnt;
        offs[n] = ebase + excl;
        float di = rsqrtf((float)cnt + 1.0f);
        dinv[n] = di;
        xpad[n] = make_float4(x[n * 3], x[n * 3 + 1], x[n * 3 + 2], di);
    }
    if (b == 0 && tid == 0) offs[NN] = NE;
    __syncthreads();
    for (int k = tid; k < m; k += 256) {
        unsigned v = part[ebase + k];
        int cl = (int)(v >> 24);
        int r = (int)(v & 0x00FFFFFFu);
        int local = atomicAdd(&cur[cl], 1);
        csr_row[ebase + lex[cl] + local] = r;
    }
}

__device__ __forceinline__ float bcast_lane(float v, int t) {
    return __uint_as_float(__builtin_amdgcn_readlane(__float_as_uint(v), (unsigned)t));
}

// Edge phase: one node per wave, halves take classes 0-4 / 5-9.
__global__ __launch_bounds__(256, 8) void edgeconv_fused(
    const float4* __restrict__ xpad, const int* __restrict__ offs,
    const int* __restrict__ csr_row, const float* __restrict__ tab,
    unsigned int* __restrict__ agg, int n_start, int n_end) {
    int lane = threadIdx.x & 63;
    int j = lane & 31;
    int half = lane >> 5;
    int c0 = half * 5;

    float A0[5], A1[5], A2[5], B0[5], B1[5], B2[5], hb[5];
#pragma unroll
    for (int i = 0; i < 5; ++i) {
        int cb = (c0 + i) * 96;
        A0[i] = tab[cb + j];       A1[i] = tab[cb + 32 + j];       A2[i] = tab[cb + 64 + j];
        B0[i] = tab[960 + cb + j]; B1[i] = tab[960 + cb + 32 + j]; B2[i] = tab[960 + cb + 64 + j];
        hb[i] = tab[1920 + (c0 + i) * 32 + j];
    }

    int wid = blockIdx.x * 4 + (threadIdx.x >> 6);
    const int wstride = gridDim.x * 4;

    for (int n = n_start + wid; n < n_end; n += wstride) {
        float4 xn = xpad[n];
        float va[5], acc[5];
#pragma unroll
        for (int i = 0; i < 5; ++i) {
            va[i] = hb[i] + xn.x * B0[i] + xn.y * B1[i] + xn.z * B2[i];
            acc[i] = 0.f;
        }
        int e0 = offs[n], e1 = offs[n + 1];
        for (int base = e0; base < e1; base += 64) {
            int ee = base + lane;
            int r = (ee < e1) ? csr_row[ee] : 0;
            float4 q = xpad[r];
            int cnt2 = e1 - base;
            if (cnt2 > 64) cnt2 = 64;
            int t = 0;
            for (; t + 1 < cnt2; t += 2) {
                float px0 = bcast_lane(q.x, t),     py0 = bcast_lane(q.y, t),     pz0 = bcast_lane(q.z, t);
                float px1 = bcast_lane(q.x, t + 1), py1 = bcast_lane(q.y, t + 1), pz1 = bcast_lane(q.z, t + 1);
#pragma unroll
                for (int i = 0; i < 5; ++i)
                    acc[i] += fmaxf(va[i] + px0 * A0[i] + py0 * A1[i] + pz0 * A2[i], 0.f);
#pragma unroll
                for (int i = 0; i < 5; ++i)
                    acc[i] += fmaxf(va[i] + px1 * A0[i] + py1 * A1[i] + pz1 * A2[i], 0.f);
            }
            if (t < cnt2) {
                float px = bcast_lane(q.x, t), py = bcast_lane(q.y, t), pz = bcast_lane(q.z, t);
#pragma unroll
                for (int i = 0; i < 5; ++i)
                    acc[i] += fmaxf(va[i] + px * A0[i] + py * A1[i] + pz * A2[i], 0.f);
            }
        }
        unsigned int* arow = agg + (unsigned)(n - n_start) * 320 + half * 160 + j;
#pragma unroll
        for (int i = 0; i < 5; ++i) {
            float a = acc[i];
            _Float16 hi = (_Float16)a;
            _Float16 lo = (_Float16)(a - (float)hi);
            half2v pr = {hi, lo};
            arow[i * 32] = __builtin_bit_cast(unsigned int, pr);
        }
    }
}

// Fold via MFMA + fused xw1-init epilogue; writes fp16 xh1 directly.
__global__ __launch_bounds__(256) void fold_mfma(
    const unsigned int* __restrict__ agg, const _Float16* __restrict__ MfragG,
    const float4* __restrict__ xpad, const int* __restrict__ ideg,
    const float* __restrict__ tab, const float* __restrict__ g1W,
    _Float16* __restrict__ xh1, int n_start, int n_end) {
    __shared__ _Float16 Mf[20480];
    {
        const uint4* src = (const uint4*)MfragG;
        uint4* dst = (uint4*)Mf;
        for (int i = threadIdx.x; i < 2560; i += 256) dst[i] = src[i];
    }
    __syncthreads();

    int wave = blockIdx.x * 4 + (threadIdx.x >> 6);
    int lane = threadIdx.x & 63;
    int n0 = n_start + wave * 16;
    if (n0 >= n_end) return;

    int m = lane & 15, q = lane >> 4;
    int arow_n = n0 + m;
    bool rowok = arow_n < n_end;
    const unsigned int* arow = agg + (unsigned)(arow_n - n_start) * 320 + q * 8;

    const half8* mf = (const half8*)Mf;
    f32x4 acc0 = {0.f, 0.f, 0.f, 0.f};
    f32x4 acc1 = {0.f, 0.f, 0.f, 0.f};

    for (int kc = 0; kc < 10; ++kc) {
        half8 ah, al;
        if (rowok) {
            uint4 w0 = *(const uint4*)(arow + kc * 32);
            uint4 w1 = *(const uint4*)(arow + kc * 32 + 4);
            unsigned int w[8] = {w0.x, w0.y, w0.z, w0.w, w1.x, w1.y, w1.z, w1.w};
#pragma unroll
            for (int i = 0; i < 8; ++i) {
                half2v pr = __builtin_bit_cast(half2v, w[i]);
                ah[i] = pr.x;
                al[i] = pr.y;
            }
        } else {
#pragma unroll
            for (int i = 0; i < 8; ++i) { ah[i] = (_Float16)0.f; al[i] = (_Float16)0.f; }
        }
        half8 bh0 = mf[((kc * 2 + 0) * 2 + 0) * 64 + lane];
        half8 bl0 = mf[((kc * 2 + 0) * 2 + 1) * 64 + lane];
        half8 bh1 = mf[((kc * 2 + 1) * 2 + 0) * 64 + lane];
        half8 bl1 = mf[((kc * 2 + 1) * 2 + 1) * 64 + lane];
        acc0 = __builtin_amdgcn_mfma_f32_16x16x32_f16(ah, bh0, acc0, 0, 0, 0);
        acc0 = __builtin_amdgcn_mfma_f32_16x16x32_f16(al, bh0, acc0, 0, 0, 0);
        acc0 = __builtin_amdgcn_mfma_f32_16x16x32_f16(ah, bl0, acc0, 0, 0, 0);
        acc1 = __builtin_amdgcn_mfma_f32_16x16x32_f16(ah, bh1, acc1, 0, 0, 0);
        acc1 = __builtin_amdgcn_mfma_f32_16x16x32_f16(al, bh1, acc1, 0, 0, 0);
        acc1 = __builtin_amdgcn_mfma_f32_16x16x32_f16(ah, bl1, acc1, 0, 0, 0);
    }

    int jcol = lane & 15;
    float t0 = tab[12480 + jcol],      t1 = tab[12480 + 16 + jcol];
    float w00 = g1W[jcol],      w01 = g1W[32 + jcol],      w02 = g1W[64 + jcol];
    float w10 = g1W[16 + jcol], w11 = g1W[48 + jcol],      w12 = g1W[80 + jcol];
#pragma unroll
    for (int r = 0; r < 4; ++r) {
        int node = n0 + q * 4 + r;
        if (node < n_end) {
            float4 xn = xpad[node];
            float dg = (float)ideg[node];
            float v0 = dg * t0 + xn.x * w00 + xn.y * w01 + xn.z * w02 + acc0[r];
            float v1 = dg * t1 + xn.x * w10 + xn.y * w11 + xn.z * w12 + acc1[r];
            xh1[node * 32 + jcol]      = (_Float16)v0;
            xh1[node * 32 + 16 + jcol] = (_Float16)v1;
        }
    }
}

// One node per wave64; half-waves take even/odd CSR slots; fp16 gather input.
__global__ __launch_bounds__(256, 4) void prop_wave(
    const int* __restrict__ offs, const int* __restrict__ csr_row,
    const _Float16* __restrict__ xh, const float* __restrict__ dinv,
    float* __restrict__ out) {
    int n = blockIdx.x * 4 + (threadIdx.x >> 6);
    if (n >= NN) return;
    int lane = threadIdx.x & 63;
    int j = lane & 31;
    int half = lane >> 5;
    int e0 = offs[n], e1 = offs[n + 1];
    float s0 = 0.f, s1 = 0.f;
    int e = e0 + half;
    for (; e + 2 < e1; e += 4) {
        int r0 = csr_row[e], r1 = csr_row[e + 2];
        s0 += (float)xh[r0 * 32 + j] * dinv[r0];
        s1 += (float)xh[r1 * 32 + j] * dinv[r1];
    }
    if (e < e1) {
        int r = csr_row[e];
        s0 += (float)xh[r * 32 + j] * dinv[r];
    }
    float s = s0 + s1;
    s += __shfl_xor(s, 32, 64);
    if (lane < 32) {
        float di = dinv[n];
        out[n * 32 + j] = di * s + di * di * (float)xh[n * 32 + j];
    }
}

// xw2: reads fp32 h1raw, writes fp16 Vh = relu(h1+b1) @ g2W
__global__ void xw2_kernel(const float* __restrict__ h1raw, const float* __restrict__ g1b,
                           const float* __restrict__ g2W, _Float16* __restrict__ Vh) {
    int gid = blockIdx.x * 256 + threadIdx.x;
    if (gid >= NN * 32) return;
    int n = gid >> 5, j = gid & 31;
    float s = 0.f;
    for (int k = 0; k < 32; ++k) {
        float h = fmaxf(h1raw[n * 32 + k] + g1b[k], 0.0f);
        s += h * g2W[k * 32 + j];
    }
    Vh[gid] = (_Float16)s;
}

__global__ void pool_seg(const float* __restrict__ h2, const float* __restrict__ g2b,
                         const int* __restrict__ batch, float* __restrict__ pooled,
                         float* __restrict__ counts) {
    int grp = threadIdx.x >> 5, j = threadIdx.x & 31;
    int base = (blockIdx.x * 8 + grp) * 64;
    if (base >= NN) return;
    float bj = g2b[j];
    float acc = 0.f, cnt = 0.f;
    int curg = -1;
    int lim = base + 64;
    if (lim > NN) lim = NN;
    for (int n = base; n < lim; ++n) {
        int g = batch[n];
        if (g != curg) {
            if (curg >= 0) {
                atomicAdd(&pooled[curg * 32 + j], acc);
                if (j == 0) atomicAdd(&counts[curg], cnt);
            }
            curg = g; acc = 0.f; cnt = 0.f;
        }
        acc += fmaxf(h2[n * 32 + j] + bj, 0.f);
        cnt += 1.f;
    }
    if (curg >= 0) {
        atomicAdd(&pooled[curg * 32 + j], acc);
        if (j == 0) atomicAdd(&counts[curg], cnt);
    }
}

__global__ void final_kernel(const float* __restrict__ pooled, const float* __restrict__ counts,
                             const float* __restrict__ clsW, const float* __restrict__ clsb,
                             float* __restrict__ out) {
    int tid = threadIdx.x;
    if (tid >= GG * CC) return;
    int g = tid / CC, cc = tid % CC;
    float inv = 1.0f / fmaxf(counts[g], 1.0f);
    float s = clsb[cc];
    for (int j = 0; j < 32; ++j) s += (pooled[g * 32 + j] * inv) * clsW[j * CC + cc];
    out[g * CC + cc] = s;
}

extern "C" void kernel_launch(void* const* d_in, const int* in_sizes, int n_in,
                              void* d_out, int out_size, void* d_ws, size_t ws_size,
                              hipStream_t stream) {
    const float* x     = (const float*)d_in[0];
    const int*   ei    = (const int*)d_in[1];
    const int*   batch = (const int*)d_in[2];
    const float* fW    = (const float*)d_in[3];
    const float* fb    = (const float*)d_in[4];
    const float* W1    = (const float*)d_in[5];
    const float* b1    = (const float*)d_in[6];
    const float* W2    = (const float*)d_in[7];
    const float* b2    = (const float*)d_in[8];
    const float* g1W   = (const float*)d_in[9];
    const float* g1b   = (const float*)d_in[10];
    const float* g2W   = (const float*)d_in[11];
    const float* g2b   = (const float*)d_in[12];
    const float* clsW  = (const float*)d_in[13];
    const float* clsb  = (const float*)d_in[14];
    float* out = (float*)d_out;

    float4*         xpad    = (float4*)d_ws;                       // 1.6 MB
    unsigned int*   agg     = (unsigned int*)(xpad + NN);          // 32 MB
    int*            csr_row = (int*)(agg + (size_t)STRIP * 320);   // 6.4 MB
    unsigned int*   part    = (unsigned int*)(csr_row + NE);       // 6.4 MB
    int*            mat     = (int*)(part + NE);                   // 156 KB
    int*            ideg    = mat + MTOT;
    int*            offs    = ideg + NN;
    float*          dinv    = (float*)(offs + NN + 1);
    float*          tab     = dinv + NN;
    _Float16*       Mfrag   = (_Float16*)(tab + 16384);            // 40 KB
    _Float16*       xh1     = Mfrag + 20480;                       // 6.4 MB
    float*          U       = (float*)(xh1 + (size_t)NN * 32);     // 12.8 MB (h1raw)
    _Float16*       Vh      = (_Float16*)(U + (size_t)NN * 32);    // 6.4 MB
    float*          h2      = (float*)(Vh + (size_t)NN * 32);      // 12.8 MB
    float*          pooled  = h2 + (size_t)NN * 32;
    float*          counts  = pooled + GG * 32;

    const int nodeBlocks = (NN * 32 + 255) / 256;
    const int waveBlocks = (NN + 3) / 4;

    zero_f<<<(GG * 33 + 255) / 256, 256, 0, stream>>>(pooled, GG * 33);
    precompute_small<<<10, 1024, 0, stream>>>(fW, fb, W1, b1, W2, b2, g1W, tab);
    mfrag_kernel<<<10, 256, 0, stream>>>(tab, Mfrag);

    // atomic-free CSR build
    bucket_hist<<<PBLK, 256, 0, stream>>>(ei, mat);
    scan_mat<<<1, 1024, 0, stream>>>(mat);
    bucket_scatter<<<PBLK, 256, 0, stream>>>(ei, mat, part);
    bucket_build<<<NB, 256, 0, stream>>>(part, mat, x, csr_row, ideg, offs, dinv, xpad);

    for (int s = 0; s < NN / STRIP; ++s) {
        int ns = s * STRIP, ne2 = ns + STRIP;
        edgeconv_fused<<<2048, 256, 0, stream>>>(xpad, offs, csr_row, tab, agg, ns, ne2);
        int foldWaves = (STRIP + 15) / 16;
        fold_mfma<<<(foldWaves + 3) / 4, 256, 0, stream>>>(agg, Mfrag, xpad, ideg, tab, g1W,
                                                           xh1, ns, ne2);
    }

    prop_wave<<<waveBlocks, 256, 0, stream>>>(offs, csr_row, xh1, dinv, U);   // h1raw
    xw2_kernel<<<nodeBlocks, 256, 0, stream>>>(U, g1b, g2W, Vh);              // xw2 fp16
    prop_wave<<<waveBlocks, 256, 0, stream>>>(offs, csr_row, Vh, dinv, h2);   // h2raw
    pool_seg<<<(NN + 511) / 512, 256, 0, stream>>>(h2, g2b, batch, pooled, counts);
    final_kernel<<<1, 640, 0, stream>>>(pooled, counts, clsW, clsb, out);
}

// Round 12
// 525.689 us; speedup vs baseline: 1.1141x; 1.1141x over previous
//
#include <hip/hip_runtime.h>

#define NN 100000
#define NE 1600000
#define HH 32
#define CC 10
#define GG 64
#define STRIP 25000
#define NB 391        // node buckets of 256 (391*256 = 100096 >= NN)
#define PBLK 100      // edge-pass blocks
#define ECH 16000     // edges per pass block (100*16000 = NE)
#define MTOT (NB * PBLK)
#define MSB ((MTOT + 255) / 256)   // 153 scan blocks for mat

typedef _Float16 half8 __attribute__((ext_vector_type(8)));
typedef _Float16 half2v __attribute__((ext_vector_type(2)));
typedef float f32x4 __attribute__((ext_vector_type(4)));

// ---------------- workspace layout ----------------
// float4 xpad[NN]; uint agg[STRIP*320]; int csr_row[NE]; uint part[NE];
// int mat[MTOT], msum[256], ideg[NN], offs[NN+1]; float dinv[NN], tab[16384];
// _Float16 Mfrag[20480]; _Float16 xh1[NN*32]; float U[NN*32]; _Float16 Vh[NN*32];
// float h2[NN*32], pooled, counts

__global__ void zero_f(float* p, int n) {
    int i = blockIdx.x * 256 + threadIdx.x;
    if (i < n) p[i] = 0.0f;
}

__global__ void precompute_small(const float* __restrict__ fW, const float* __restrict__ fb,
                                 const float* __restrict__ W1, const float* __restrict__ b1,
                                 const float* __restrict__ W2, const float* __restrict__ b2,
                                 const float* __restrict__ g1W, float* __restrict__ tab) {
    int c = blockIdx.x;
    int k = threadIdx.x >> 5;
    int j = threadIdx.x & 31;
    float m = 0.f;
    for (int mm = 0; mm < 32; ++mm)
        m += W2[k * 32 + mm] * g1W[(3 + 32 * c + mm) * 32 + j];
    tab[2240 + c * 1024 + k * 32 + j] = m;

    if (k < 3) {
        float a = 0.f, b = 0.f;
        for (int i = 0; i < 32; ++i) {
            float w = fW[c * 96 + k * 32 + i];
            a += w * W1[i * 32 + j];
            b += w * W1[(32 + i) * 32 + j];
        }
        tab[c * 96 + k * 32 + j] = a;
        tab[960 + c * 96 + k * 32 + j] = b;
    } else if (k == 3) {
        float h = b1[j];
        for (int i = 0; i < 32; ++i)
            h += fb[c * 32 + i] * (W1[i * 32 + j] + W1[(32 + i) * 32 + j]);
        tab[1920 + c * 32 + j] = h;
    } else if (k == 4 && c == 0) {
        float t = 0.f;
        for (int cc2 = 0; cc2 < CC; ++cc2)
            for (int mm = 0; mm < 32; ++mm)
                t += b2[mm] * g1W[(3 + 32 * cc2 + mm) * 32 + j];
        tab[12480 + j] = t;
    }
}

// Pre-swizzle Mflat[320][32] into MFMA B-fragment order, fp16 hi/lo planes.
__global__ void mfrag_kernel(const float* __restrict__ tab, _Float16* __restrict__ Mfrag) {
    int gid = blockIdx.x * 256 + threadIdx.x;   // [0, 2560)
    if (gid >= 2560) return;
    int set = gid >> 6, l = gid & 63;
    int p = set & 1, jt = (set >> 1) & 1, kc = set >> 2;
    int j = jt * 16 + (l & 15);
    int kbase = kc * 32 + (l >> 4) * 8;
#pragma unroll
    for (int i = 0; i < 8; ++i) {
        float v = tab[2240 + (kbase + i) * 32 + j];
        _Float16 hi = (_Float16)v;
        Mfrag[gid * 8 + i] = p ? (_Float16)(v - (float)hi) : hi;
    }
}

// ---- atomic-free CSR build: bucketed counting sort (LDS atomics only) ----
// P1: per-block LDS histogram over NB buckets (bucket = col >> 8)
__global__ void bucket_hist(const int* __restrict__ ei, int* __restrict__ mat) {
    __shared__ int h[NB];
    int blk = blockIdx.x, tid = threadIdx.x;
    for (int i = tid; i < NB; i += 256) h[i] = 0;
    __syncthreads();
    int base = blk * ECH;
    for (int k = tid; k < ECH; k += 256)
        atomicAdd(&h[ei[NE + base + k] >> 8], 1);
    __syncthreads();
    for (int i = tid; i < NB; i += 256) mat[i * PBLK + blk] = h[i];
}

// P2: hierarchical exclusive scan of mat[MTOT] (3 phases, all parallel)
__global__ void scan_m1(const int* __restrict__ mat, int* __restrict__ msum) {
    __shared__ int sh[256];
    int b = blockIdx.x, t = threadIdx.x;
    int i = b * 256 + t;
    sh[t] = (i < MTOT) ? mat[i] : 0;
    __syncthreads();
    for (int off = 128; off > 0; off >>= 1) {
        if (t < off) sh[t] += sh[t + off];
        __syncthreads();
    }
    if (t == 0) msum[b] = sh[0];
}

__global__ void scan_m2(int* __restrict__ msum) {
    __shared__ int sh[256];
    int t = threadIdx.x;
    int v = (t < MSB) ? msum[t] : 0;
    sh[t] = v;
    __syncthreads();
    for (int off = 1; off < 256; off <<= 1) {
        int add = (t >= off) ? sh[t - off] : 0;
        __syncthreads();
        sh[t] += add;
        __syncthreads();
    }
    if (t < MSB) msum[t] = sh[t] - v;   // exclusive
}

__global__ void scan_m3(int* __restrict__ mat, const int* __restrict__ msum) {
    __shared__ int sh[256];
    int b = blockIdx.x, t = threadIdx.x;
    int i = b * 256 + t;
    int v = (i < MTOT) ? mat[i] : 0;
    sh[t] = v;
    __syncthreads();
    for (int off = 1; off < 256; off <<= 1) {
        int add = (t >= off) ? sh[t - off] : 0;
        __syncthreads();
        sh[t] += add;
        __syncthreads();
    }
    if (i < MTOT) mat[i] = sh[t] - v + msum[b];
}

// P3: scatter edges into bucket-partitioned part[]; packed r | (c_local<<24)
__global__ void bucket_scatter(const int* __restrict__ ei, const int* __restrict__ mat,
                               unsigned int* __restrict__ part) {
    __shared__ int bas[NB];
    __shared__ int cur[NB];
    int blk = blockIdx.x, tid = threadIdx.x;
    for (int i = tid; i < NB; i += 256) { bas[i] = mat[i * PBLK + blk]; cur[i] = 0; }
    __syncthreads();
    int base = blk * ECH;
    for (int k = tid; k < ECH; k += 256) {
        int e = base + k;
        int r = ei[e];
        int c = ei[NE + e];
        int b = c >> 8;
        int local = atomicAdd(&cur[b], 1);
        part[bas[b] + local] = (unsigned)r | ((unsigned)(c & 255) << 24);
    }
}

// P4: per-bucket (256 nodes) histogram+scan in LDS; writes ideg/offs/dinv/xpad
// coalesced and csr_row grouped by node. No global atomics.
__global__ void bucket_build(const unsigned int* __restrict__ part, const int* __restrict__ mat,
                             const float* __restrict__ x, int* __restrict__ csr_row,
                             int* __restrict__ ideg, int* __restrict__ offs,
                             float* __restrict__ dinv, float4* __restrict__ xpad) {
    __shared__ int lh[256];
    __shared__ int lex[256];
    __shared__ int cur[256];
    int b = blockIdx.x, tid = threadIdx.x;
    int ebase = mat[b * PBLK];
    int eend = (b == NB - 1) ? NE : mat[(b + 1) * PBLK];
    int m = eend - ebase;
    lh[tid] = 0;
    __syncthreads();
    for (int k = tid; k < m; k += 256) {
        unsigned v = part[ebase + k];
        atomicAdd(&lh[v >> 24], 1);
    }
    __syncthreads();
    int cnt = lh[tid];
    lex[tid] = cnt;
    __syncthreads();
    for (int off = 1; off < 256; off <<= 1) {
        int v = (tid >= off) ? lex[tid - off] : 0;
        __syncthreads();
        lex[tid] += v;
        __syncthreads();
    }
    int excl = lex[tid] - cnt;
    lex[tid] = excl;
    cur[tid] = 0;
    int n = b * 256 + tid;
    if (n < NN) {
        ideg[n] = cnt;
        offs[n] = ebase + excl;
        float di = rsqrtf((float)cnt + 1.0f);
        dinv[n] = di;
        xpad[n] = make_float4(x[n * 3], x[n * 3 + 1], x[n * 3 + 2], di);
    }
    if (b == 0 && tid == 0) offs[NN] = NE;
    __syncthreads();
    for (int k = tid; k < m; k += 256) {
        unsigned v = part[ebase + k];
        int cl = (int)(v >> 24);
        int r = (int)(v & 0x00FFFFFFu);
        int local = atomicAdd(&cur[cl], 1);
        csr_row[ebase + lex[cl] + local] = r;
    }
}

__device__ __forceinline__ float bcast_lane(float v, int t) {
    return __uint_as_float(__builtin_amdgcn_readlane(__float_as_uint(v), (unsigned)t));
}

// Edge phase: one node per wave, halves take classes 0-4 / 5-9.
__global__ __launch_bounds__(256, 8) void edgeconv_fused(
    const float4* __restrict__ xpad, const int* __restrict__ offs,
    const int* __restrict__ csr_row, const float* __restrict__ tab,
    unsigned int* __restrict__ agg, int n_start, int n_end) {
    int lane = threadIdx.x & 63;
    int j = lane & 31;
    int half = lane >> 5;
    int c0 = half * 5;

    float A0[5], A1[5], A2[5], B0[5], B1[5], B2[5], hb[5];
#pragma unroll
    for (int i = 0; i < 5; ++i) {
        int cb = (c0 + i) * 96;
        A0[i] = tab[cb + j];       A1[i] = tab[cb + 32 + j];       A2[i] = tab[cb + 64 + j];
        B0[i] = tab[960 + cb + j]; B1[i] = tab[960 + cb + 32 + j]; B2[i] = tab[960 + cb + 64 + j];
        hb[i] = tab[1920 + (c0 + i) * 32 + j];
    }

    int wid = blockIdx.x * 4 + (threadIdx.x >> 6);
    const int wstride = gridDim.x * 4;

    for (int n = n_start + wid; n < n_end; n += wstride) {
        float4 xn = xpad[n];
        float va[5], acc[5];
#pragma unroll
        for (int i = 0; i < 5; ++i) {
            va[i] = hb[i] + xn.x * B0[i] + xn.y * B1[i] + xn.z * B2[i];
            acc[i] = 0.f;
        }
        int e0 = offs[n], e1 = offs[n + 1];
        for (int base = e0; base < e1; base += 64) {
            int ee = base + lane;
            int r = (ee < e1) ? csr_row[ee] : 0;
            float4 q = xpad[r];
            int cnt2 = e1 - base;
            if (cnt2 > 64) cnt2 = 64;
            int t = 0;
            for (; t + 1 < cnt2; t += 2) {
                float px0 = bcast_lane(q.x, t),     py0 = bcast_lane(q.y, t),     pz0 = bcast_lane(q.z, t);
                float px1 = bcast_lane(q.x, t + 1), py1 = bcast_lane(q.y, t + 1), pz1 = bcast_lane(q.z, t + 1);
#pragma unroll
                for (int i = 0; i < 5; ++i)
                    acc[i] += fmaxf(va[i] + px0 * A0[i] + py0 * A1[i] + pz0 * A2[i], 0.f);
#pragma unroll
                for (int i = 0; i < 5; ++i)
                    acc[i] += fmaxf(va[i] + px1 * A0[i] + py1 * A1[i] + pz1 * A2[i], 0.f);
            }
            if (t < cnt2) {
                float px = bcast_lane(q.x, t), py = bcast_lane(q.y, t), pz = bcast_lane(q.z, t);
#pragma unroll
                for (int i = 0; i < 5; ++i)
                    acc[i] += fmaxf(va[i] + px * A0[i] + py * A1[i] + pz * A2[i], 0.f);
            }
        }
        unsigned int* arow = agg + (unsigned)(n - n_start) * 320 + half * 160 + j;
#pragma unroll
        for (int i = 0; i < 5; ++i) {
            float a = acc[i];
            _Float16 hi = (_Float16)a;
            _Float16 lo = (_Float16)(a - (float)hi);
            half2v pr = {hi, lo};
            arow[i * 32] = __builtin_bit_cast(unsigned int, pr);
        }
    }
}

// Fold via MFMA + fused xw1-init epilogue; writes fp16 xh1 directly.
__global__ __launch_bounds__(256) void fold_mfma(
    const unsigned int* __restrict__ agg, const _Float16* __restrict__ MfragG,
    const float4* __restrict__ xpad, const int* __restrict__ ideg,
    const float* __restrict__ tab, const float* __restrict__ g1W,
    _Float16* __restrict__ xh1, int n_start, int n_end) {
    __shared__ _Float16 Mf[20480];
    {
        const uint4* src = (const uint4*)MfragG;
        uint4* dst = (uint4*)Mf;
        for (int i = threadIdx.x; i < 2560; i += 256) dst[i] = src[i];
    }
    __syncthreads();

    int wave = blockIdx.x * 4 + (threadIdx.x >> 6);
    int lane = threadIdx.x & 63;
    int n0 = n_start + wave * 16;
    if (n0 >= n_end) return;

    int m = lane & 15, q = lane >> 4;
    int arow_n = n0 + m;
    bool rowok = arow_n < n_end;
    const unsigned int* arow = agg + (unsigned)(arow_n - n_start) * 320 + q * 8;

    const half8* mf = (const half8*)Mf;
    f32x4 acc0 = {0.f, 0.f, 0.f, 0.f};
    f32x4 acc1 = {0.f, 0.f, 0.f, 0.f};

    for (int kc = 0; kc < 10; ++kc) {
        half8 ah, al;
        if (rowok) {
            uint4 w0 = *(const uint4*)(arow + kc * 32);
            uint4 w1 = *(const uint4*)(arow + kc * 32 + 4);
            unsigned int w[8] = {w0.x, w0.y, w0.z, w0.w, w1.x, w1.y, w1.z, w1.w};
#pragma unroll
            for (int i = 0; i < 8; ++i) {
                half2v pr = __builtin_bit_cast(half2v, w[i]);
                ah[i] = pr.x;
                al[i] = pr.y;
            }
        } else {
#pragma unroll
            for (int i = 0; i < 8; ++i) { ah[i] = (_Float16)0.f; al[i] = (_Float16)0.f; }
        }
        half8 bh0 = mf[((kc * 2 + 0) * 2 + 0) * 64 + lane];
        half8 bl0 = mf[((kc * 2 + 0) * 2 + 1) * 64 + lane];
        half8 bh1 = mf[((kc * 2 + 1) * 2 + 0) * 64 + lane];
        half8 bl1 = mf[((kc * 2 + 1) * 2 + 1) * 64 + lane];
        acc0 = __builtin_amdgcn_mfma_f32_16x16x32_f16(ah, bh0, acc0, 0, 0, 0);
        acc0 = __builtin_amdgcn_mfma_f32_16x16x32_f16(al, bh0, acc0, 0, 0, 0);
        acc0 = __builtin_amdgcn_mfma_f32_16x16x32_f16(ah, bl0, acc0, 0, 0, 0);
        acc1 = __builtin_amdgcn_mfma_f32_16x16x32_f16(ah, bh1, acc1, 0, 0, 0);
        acc1 = __builtin_amdgcn_mfma_f32_16x16x32_f16(al, bh1, acc1, 0, 0, 0);
        acc1 = __builtin_amdgcn_mfma_f32_16x16x32_f16(ah, bl1, acc1, 0, 0, 0);
    }

    int jcol = lane & 15;
    float t0 = tab[12480 + jcol],      t1 = tab[12480 + 16 + jcol];
    float w00 = g1W[jcol],      w01 = g1W[32 + jcol],      w02 = g1W[64 + jcol];
    float w10 = g1W[16 + jcol], w11 = g1W[48 + jcol],      w12 = g1W[80 + jcol];
#pragma unroll
    for (int r = 0; r < 4; ++r) {
        int node = n0 + q * 4 + r;
        if (node < n_end) {
            float4 xn = xpad[node];
            float dg = (float)ideg[node];
            float v0 = dg * t0 + xn.x * w00 + xn.y * w01 + xn.z * w02 + acc0[r];
            float v1 = dg * t1 + xn.x * w10 + xn.y * w11 + xn.z * w12 + acc1[r];
            xh1[node * 32 + jcol]      = (_Float16)v0;
            xh1[node * 32 + 16 + jcol] = (_Float16)v1;
        }
    }
}

// One node per wave64; half-waves take even/odd CSR slots; fp16 gather input.
__global__ __launch_bounds__(256, 4) void prop_wave(
    const int* __restrict__ offs, const int* __restrict__ csr_row,
    const _Float16* __restrict__ xh, const float* __restrict__ dinv,
    float* __restrict__ out) {
    int n = blockIdx.x * 4 + (threadIdx.x >> 6);
    if (n >= NN) return;
    int lane = threadIdx.x & 63;
    int j = lane & 31;
    int half = lane >> 5;
    int e0 = offs[n], e1 = offs[n + 1];
    float s0 = 0.f, s1 = 0.f;
    int e = e0 + half;
    for (; e + 2 < e1; e += 4) {
        int r0 = csr_row[e], r1 = csr_row[e + 2];
        s0 += (float)xh[r0 * 32 + j] * dinv[r0];
        s1 += (float)xh[r1 * 32 + j] * dinv[r1];
    }
    if (e < e1) {
        int r = csr_row[e];
        s0 += (float)xh[r * 32 + j] * dinv[r];
    }
    float s = s0 + s1;
    s += __shfl_xor(s, 32, 64);
    if (lane < 32) {
        float di = dinv[n];
        out[n * 32 + j] = di * s + di * di * (float)xh[n * 32 + j];
    }
}

// xw2: reads fp32 h1raw, writes fp16 Vh = relu(h1+b1) @ g2W
__global__ void xw2_kernel(const float* __restrict__ h1raw, const float* __restrict__ g1b,
                           const float* __restrict__ g2W, _Float16* __restrict__ Vh) {
    int gid = blockIdx.x * 256 + threadIdx.x;
    if (gid >= NN * 32) return;
    int n = gid >> 5, j = gid & 31;
    float s = 0.f;
    for (int k = 0; k < 32; ++k) {
        float h = fmaxf(h1raw[n * 32 + k] + g1b[k], 0.0f);
        s += h * g2W[k * 32 + j];
    }
    Vh[gid] = (_Float16)s;
}

__global__ void pool_seg(const float* __restrict__ h2, const float* __restrict__ g2b,
                         const int* __restrict__ batch, float* __restrict__ pooled,
                         float* __restrict__ counts) {
    int grp = threadIdx.x >> 5, j = threadIdx.x & 31;
    int base = (blockIdx.x * 8 + grp) * 64;
    if (base >= NN) return;
    float bj = g2b[j];
    float acc = 0.f, cnt = 0.f;
    int curg = -1;
    int lim = base + 64;
    if (lim > NN) lim = NN;
    for (int n = base; n < lim; ++n) {
        int g = batch[n];
        if (g != curg) {
            if (curg >= 0) {
                atomicAdd(&pooled[curg * 32 + j], acc);
                if (j == 0) atomicAdd(&counts[curg], cnt);
            }
            curg = g; acc = 0.f; cnt = 0.f;
        }
        acc += fmaxf(h2[n * 32 + j] + bj, 0.f);
        cnt += 1.f;
    }
    if (curg >= 0) {
        atomicAdd(&pooled[curg * 32 + j], acc);
        if (j == 0) atomicAdd(&counts[curg], cnt);
    }
}

__global__ void final_kernel(const float* __restrict__ pooled, const float* __restrict__ counts,
                             const float* __restrict__ clsW, const float* __restrict__ clsb,
                             float* __restrict__ out) {
    int tid = threadIdx.x;
    if (tid >= GG * CC) return;
    int g = tid / CC, cc = tid % CC;
    float inv = 1.0f / fmaxf(counts[g], 1.0f);
    float s = clsb[cc];
    for (int j = 0; j < 32; ++j) s += (pooled[g * 32 + j] * inv) * clsW[j * CC + cc];
    out[g * CC + cc] = s;
}

extern "C" void kernel_launch(void* const* d_in, const int* in_sizes, int n_in,
                              void* d_out, int out_size, void* d_ws, size_t ws_size,
                              hipStream_t stream) {
    const float* x     = (const float*)d_in[0];
    const int*   ei    = (const int*)d_in[1];
    const int*   batch = (const int*)d_in[2];
    const float* fW    = (const float*)d_in[3];
    const float* fb    = (const float*)d_in[4];
    const float* W1    = (const float*)d_in[5];
    const float* b1    = (const float*)d_in[6];
    const float* W2    = (const float*)d_in[7];
    const float* b2    = (const float*)d_in[8];
    const float* g1W   = (const float*)d_in[9];
    const float* g1b   = (const float*)d_in[10];
    const float* g2W   = (const float*)d_in[11];
    const float* g2b   = (const float*)d_in[12];
    const float* clsW  = (const float*)d_in[13];
    const float* clsb  = (const float*)d_in[14];
    float* out = (float*)d_out;

    float4*         xpad    = (float4*)d_ws;                       // 1.6 MB
    unsigned int*   agg     = (unsigned int*)(xpad + NN);          // 32 MB
    int*            csr_row = (int*)(agg + (size_t)STRIP * 320);   // 6.4 MB
    unsigned int*   part    = (unsigned int*)(csr_row + NE);       // 6.4 MB
    int*            mat     = (int*)(part + NE);                   // 156 KB
    int*            msum    = mat + MTOT;                          // 256 ints
    int*            ideg    = msum + 256;
    int*            offs    = ideg + NN;
    float*          dinv    = (float*)(offs + NN + 1);
    float*          tab     = dinv + NN;
    _Float16*       Mfrag   = (_Float16*)(tab + 16384);            // 40 KB
    _Float16*       xh1     = Mfrag + 20480;                       // 6.4 MB
    float*          U       = (float*)(xh1 + (size_t)NN * 32);     // 12.8 MB (h1raw)
    _Float16*       Vh      = (_Float16*)(U + (size_t)NN * 32);    // 6.4 MB
    float*          h2      = (float*)(Vh + (size_t)NN * 32);      // 12.8 MB
    float*          pooled  = h2 + (size_t)NN * 32;
    float*          counts  = pooled + GG * 32;

    const int nodeBlocks = (NN * 32 + 255) / 256;
    const int waveBlocks = (NN + 3) / 4;

    zero_f<<<(GG * 33 + 255) / 256, 256, 0, stream>>>(pooled, GG * 33);
    precompute_small<<<10, 1024, 0, stream>>>(fW, fb, W1, b1, W2, b2, g1W, tab);
    mfrag_kernel<<<10, 256, 0, stream>>>(tab, Mfrag);

    // atomic-free CSR build (hierarchical mat-scan)
    bucket_hist<<<PBLK, 256, 0, stream>>>(ei, mat);
    scan_m1<<<MSB, 256, 0, stream>>>(mat, msum);
    scan_m2<<<1, 256, 0, stream>>>(msum);
    scan_m3<<<MSB, 256, 0, stream>>>(mat, msum);
    bucket_scatter<<<PBLK, 256, 0, stream>>>(ei, mat, part);
    bucket_build<<<NB, 256, 0, stream>>>(part, mat, x, csr_row, ideg, offs, dinv, xpad);

    for (int s = 0; s < NN / STRIP; ++s) {
        int ns = s * STRIP, ne2 = ns + STRIP;
        edgeconv_fused<<<2048, 256, 0, stream>>>(xpad, offs, csr_row, tab, agg, ns, ne2);
        int foldWaves = (STRIP + 15) / 16;
        fold_mfma<<<(foldWaves + 3) / 4, 256, 0, stream>>>(agg, Mfrag, xpad, ideg, tab, g1W,
                                                           xh1, ns, ne2);
    }

    prop_wave<<<waveBlocks, 256, 0, stream>>>(offs, csr_row, xh1, dinv, U);   // h1raw
    xw2_kernel<<<nodeBlocks, 256, 0, stream>>>(U, g1b, g2W, Vh);              // xw2 fp16
    prop_wave<<<waveBlocks, 256, 0, stream>>>(offs, csr_row, Vh, dinv, h2);   // h2raw
    pool_seg<<<(NN + 511) / 512, 256, 0, stream>>>(h2, g2b, batch, pooled, counts);
    final_kernel<<<1, 640, 0, stream>>>(pooled, counts, clsW, clsb, out);
}

// Round 13
// 476.660 us; speedup vs baseline: 1.2286x; 1.1029x over previous
//
#include <hip/hip_runtime.h>

#define NN 100000
#define NE 1600000
#define HH 32
#define CC 10
#define GG 64
#define STRIP 25000
#define NB 391        // node buckets of 256
#define PBLK 100      // edge-pass blocks
#define ECH 16000     // edges per pass block
#define MTOT (NB * PBLK)
#define MSB ((MTOT + 255) / 256)

typedef _Float16 half8 __attribute__((ext_vector_type(8)));
typedef _Float16 half2v __attribute__((ext_vector_type(2)));
typedef float f32x4 __attribute__((ext_vector_type(4)));

__global__ void zero_f(float* p, int n) {
    int i = blockIdx.x * 256 + threadIdx.x;
    if (i < n) p[i] = 0.0f;
}

__global__ void precompute_small(const float* __restrict__ fW, const float* __restrict__ fb,
                                 const float* __restrict__ W1, const float* __restrict__ b1,
                                 const float* __restrict__ W2, const float* __restrict__ b2,
                                 const float* __restrict__ g1W, float* __restrict__ tab) {
    int c = blockIdx.x;
    int k = threadIdx.x >> 5;
    int j = threadIdx.x & 31;
    float m = 0.f;
    for (int mm = 0; mm < 32; ++mm)
        m += W2[k * 32 + mm] * g1W[(3 + 32 * c + mm) * 32 + j];
    tab[2240 + c * 1024 + k * 32 + j] = m;

    if (k < 3) {
        float a = 0.f, b = 0.f;
        for (int i = 0; i < 32; ++i) {
            float w = fW[c * 96 + k * 32 + i];
            a += w * W1[i * 32 + j];
            b += w * W1[(32 + i) * 32 + j];
        }
        tab[c * 96 + k * 32 + j] = a;
        tab[960 + c * 96 + k * 32 + j] = b;
    } else if (k == 3) {
        float h = b1[j];
        for (int i = 0; i < 32; ++i)
            h += fb[c * 32 + i] * (W1[i * 32 + j] + W1[(32 + i) * 32 + j]);
        tab[1920 + c * 32 + j] = h;
    } else if (k == 4 && c == 0) {
        float t = 0.f;
        for (int cc2 = 0; cc2 < CC; ++cc2)
            for (int mm = 0; mm < 32; ++mm)
                t += b2[mm] * g1W[(3 + 32 * cc2 + mm) * 32 + j];
        tab[12480 + j] = t;
    }
}

__global__ void mfrag_kernel(const float* __restrict__ tab, _Float16* __restrict__ Mfrag) {
    int gid = blockIdx.x * 256 + threadIdx.x;
    if (gid >= 2560) return;
    int set = gid >> 6, l = gid & 63;
    int p = set & 1, jt = (set >> 1) & 1, kc = set >> 2;
    int j = jt * 16 + (l & 15);
    int kbase = kc * 32 + (l >> 4) * 8;
#pragma unroll
    for (int i = 0; i < 8; ++i) {
        float v = tab[2240 + (kbase + i) * 32 + j];
        _Float16 hi = (_Float16)v;
        Mfrag[gid * 8 + i] = p ? (_Float16)(v - (float)hi) : hi;
    }
}

// ---- atomic-free CSR build ----
__global__ void bucket_hist(const int* __restrict__ ei, int* __restrict__ mat) {
    __shared__ int h[NB];
    int blk = blockIdx.x, tid = threadIdx.x;
    for (int i = tid; i < NB; i += 256) h[i] = 0;
    __syncthreads();
    int base = blk * ECH;
    for (int k = tid; k < ECH; k += 256)
        atomicAdd(&h[ei[NE + base + k] >> 8], 1);
    __syncthreads();
    for (int i = tid; i < NB; i += 256) mat[i * PBLK + blk] = h[i];
}

__global__ void scan_m1(const int* __restrict__ mat, int* __restrict__ msum) {
    __shared__ int sh[256];
    int b = blockIdx.x, t = threadIdx.x;
    int i = b * 256 + t;
    sh[t] = (i < MTOT) ? mat[i] : 0;
    __syncthreads();
    for (int off = 128; off > 0; off >>= 1) {
        if (t < off) sh[t] += sh[t + off];
        __syncthreads();
    }
    if (t == 0) msum[b] = sh[0];
}

__global__ void scan_m2(int* __restrict__ msum) {
    __shared__ int sh[256];
    int t = threadIdx.x;
    int v = (t < MSB) ? msum[t] : 0;
    sh[t] = v;
    __syncthreads();
    for (int off = 1; off < 256; off <<= 1) {
        int add = (t >= off) ? sh[t - off] : 0;
        __syncthreads();
        sh[t] += add;
        __syncthreads();
    }
    if (t < MSB) msum[t] = sh[t] - v;
}

__global__ void scan_m3(int* __restrict__ mat, const int* __restrict__ msum) {
    __shared__ int sh[256];
    int b = blockIdx.x, t = threadIdx.x;
    int i = b * 256 + t;
    int v = (i < MTOT) ? mat[i] : 0;
    sh[t] = v;
    __syncthreads();
    for (int off = 1; off < 256; off <<= 1) {
        int add = (t >= off) ? sh[t - off] : 0;
        __syncthreads();
        sh[t] += add;
        __syncthreads();
    }
    if (i < MTOT) mat[i] = sh[t] - v + msum[b];
}

__global__ void bucket_scatter(const int* __restrict__ ei, const int* __restrict__ mat,
                               unsigned int* __restrict__ part) {
    __shared__ int bas[NB];
    __shared__ int cur[NB];
    int blk = blockIdx.x, tid = threadIdx.x;
    for (int i = tid; i < NB; i += 256) { bas[i] = mat[i * PBLK + blk]; cur[i] = 0; }
    __syncthreads();
    int base = blk * ECH;
    for (int k = tid; k < ECH; k += 256) {
        int e = base + k;
        int r = ei[e];
        int c = ei[NE + e];
        int b = c >> 8;
        int local = atomicAdd(&cur[b], 1);
        part[bas[b] + local] = (unsigned)r | ((unsigned)(c & 255) << 24);
    }
}

__global__ void bucket_build(const unsigned int* __restrict__ part, const int* __restrict__ mat,
                             const float* __restrict__ x, int* __restrict__ csr_row,
                             int* __restrict__ ideg, int* __restrict__ offs,
                             float* __restrict__ dinv, float4* __restrict__ xpad) {
    __shared__ int lh[256];
    __shared__ int lex[256];
    __shared__ int cur[256];
    int b = blockIdx.x, tid = threadIdx.x;
    int ebase = mat[b * PBLK];
    int eend = (b == NB - 1) ? NE : mat[(b + 1) * PBLK];
    int m = eend - ebase;
    lh[tid] = 0;
    __syncthreads();
    for (int k = tid; k < m; k += 256) {
        unsigned v = part[ebase + k];
        atomicAdd(&lh[v >> 24], 1);
    }
    __syncthreads();
    int cnt = lh[tid];
    lex[tid] = cnt;
    __syncthreads();
    for (int off = 1; off < 256; off <<= 1) {
        int v = (tid >= off) ? lex[tid - off] : 0;
        __syncthreads();
        lex[tid] += v;
        __syncthreads();
    }
    int excl = lex[tid] - cnt;
    lex[tid] = excl;
    cur[tid] = 0;
    int n = b * 256 + tid;
    if (n < NN) {
        ideg[n] = cnt;
        offs[n] = ebase + excl;
        float di = rsqrtf((float)cnt + 1.0f);
        dinv[n] = di;
        xpad[n] = make_float4(x[n * 3], x[n * 3 + 1], x[n * 3 + 2], di);
    }
    if (b == 0 && tid == 0) offs[NN] = NE;
    __syncthreads();
    for (int k = tid; k < m; k += 256) {
        unsigned v = part[ebase + k];
        int cl = (int)(v >> 24);
        int r = (int)(v & 0x00FFFFFFu);
        int local = atomicAdd(&cur[cl], 1);
        csr_row[ebase + lex[cl] + local] = r;
    }
}

__device__ __forceinline__ float bcast_lane(float v, int t) {
    return __uint_as_float(__builtin_amdgcn_readlane(__float_as_uint(v), (unsigned)t));
}

// Edge phase: one node per wave, halves take classes 0-4 / 5-9.
__global__ __launch_bounds__(256, 8) void edgeconv_fused(
    const float4* __restrict__ xpad, const int* __restrict__ offs,
    const int* __restrict__ csr_row, const float* __restrict__ tab,
    unsigned int* __restrict__ agg, int n_start, int n_end) {
    int lane = threadIdx.x & 63;
    int j = lane & 31;
    int half = lane >> 5;
    int c0 = half * 5;

    float A0[5], A1[5], A2[5], B0[5], B1[5], B2[5], hb[5];
#pragma unroll
    for (int i = 0; i < 5; ++i) {
        int cb = (c0 + i) * 96;
        A0[i] = tab[cb + j];       A1[i] = tab[cb + 32 + j];       A2[i] = tab[cb + 64 + j];
        B0[i] = tab[960 + cb + j]; B1[i] = tab[960 + cb + 32 + j]; B2[i] = tab[960 + cb + 64 + j];
        hb[i] = tab[1920 + (c0 + i) * 32 + j];
    }

    int wid = blockIdx.x * 4 + (threadIdx.x >> 6);
    const int wstride = gridDim.x * 4;

    for (int n = n_start + wid; n < n_end; n += wstride) {
        float4 xn = xpad[n];
        float va[5], acc[5];
#pragma unroll
        for (int i = 0; i < 5; ++i) {
            va[i] = hb[i] + xn.x * B0[i] + xn.y * B1[i] + xn.z * B2[i];
            acc[i] = 0.f;
        }
        int e0 = offs[n], e1 = offs[n + 1];
        for (int base = e0; base < e1; base += 64) {
            int ee = base + lane;
            int r = (ee < e1) ? csr_row[ee] : 0;
            float4 q = xpad[r];
            int cnt2 = e1 - base;
            if (cnt2 > 64) cnt2 = 64;
            int t = 0;
            for (; t + 1 < cnt2; t += 2) {
                float px0 = bcast_lane(q.x, t),     py0 = bcast_lane(q.y, t),     pz0 = bcast_lane(q.z, t);
                float px1 = bcast_lane(q.x, t + 1), py1 = bcast_lane(q.y, t + 1), pz1 = bcast_lane(q.z, t + 1);
#pragma unroll
                for (int i = 0; i < 5; ++i)
                    acc[i] += fmaxf(va[i] + px0 * A0[i] + py0 * A1[i] + pz0 * A2[i], 0.f);
#pragma unroll
                for (int i = 0; i < 5; ++i)
                    acc[i] += fmaxf(va[i] + px1 * A0[i] + py1 * A1[i] + pz1 * A2[i], 0.f);
            }
            if (t < cnt2) {
                float px = bcast_lane(q.x, t), py = bcast_lane(q.y, t), pz = bcast_lane(q.z, t);
#pragma unroll
                for (int i = 0; i < 5; ++i)
                    acc[i] += fmaxf(va[i] + px * A0[i] + py * A1[i] + pz * A2[i], 0.f);
            }
        }
        unsigned int* arow = agg + (unsigned)(n - n_start) * 320 + half * 160 + j;
#pragma unroll
        for (int i = 0; i < 5; ++i) {
            float a = acc[i];
            _Float16 hi = (_Float16)a;
            _Float16 lo = (_Float16)(a - (float)hi);
            half2v pr = {hi, lo};
            arow[i * 32] = __builtin_bit_cast(unsigned int, pr);
        }
    }
}

// Fold via MFMA + fused xw1-init epilogue; writes fp16 xh1 directly.
__global__ __launch_bounds__(256) void fold_mfma(
    const unsigned int* __restrict__ agg, const _Float16* __restrict__ MfragG,
    const float4* __restrict__ xpad, const int* __restrict__ ideg,
    const float* __restrict__ tab, const float* __restrict__ g1W,
    _Float16* __restrict__ xh1, int n_start, int n_end) {
    __shared__ _Float16 Mf[20480];
    {
        const uint4* src = (const uint4*)MfragG;
        uint4* dst = (uint4*)Mf;
        for (int i = threadIdx.x; i < 2560; i += 256) dst[i] = src[i];
    }
    __syncthreads();

    int wave = blockIdx.x * 4 + (threadIdx.x >> 6);
    int lane = threadIdx.x & 63;
    int n0 = n_start + wave * 16;
    if (n0 >= n_end) return;

    int m = lane & 15, q = lane >> 4;
    int arow_n = n0 + m;
    bool rowok = arow_n < n_end;
    const unsigned int* arow = agg + (unsigned)(arow_n - n_start) * 320 + q * 8;

    const half8* mf = (const half8*)Mf;
    f32x4 acc0 = {0.f, 0.f, 0.f, 0.f};
    f32x4 acc1 = {0.f, 0.f, 0.f, 0.f};

    for (int kc = 0; kc < 10; ++kc) {
        half8 ah, al;
        if (rowok) {
            uint4 w0 = *(const uint4*)(arow + kc * 32);
            uint4 w1 = *(const uint4*)(arow + kc * 32 + 4);
            unsigned int w[8] = {w0.x, w0.y, w0.z, w0.w, w1.x, w1.y, w1.z, w1.w};
#pragma unroll
            for (int i = 0; i < 8; ++i) {
                half2v pr = __builtin_bit_cast(half2v, w[i]);
                ah[i] = pr.x;
                al[i] = pr.y;
            }
        } else {
#pragma unroll
            for (int i = 0; i < 8; ++i) { ah[i] = (_Float16)0.f; al[i] = (_Float16)0.f; }
        }
        half8 bh0 = mf[((kc * 2 + 0) * 2 + 0) * 64 + lane];
        half8 bl0 = mf[((kc * 2 + 0) * 2 + 1) * 64 + lane];
        half8 bh1 = mf[((kc * 2 + 1) * 2 + 0) * 64 + lane];
        half8 bl1 = mf[((kc * 2 + 1) * 2 + 1) * 64 + lane];
        acc0 = __builtin_amdgcn_mfma_f32_16x16x32_f16(ah, bh0, acc0, 0, 0, 0);
        acc0 = __builtin_amdgcn_mfma_f32_16x16x32_f16(al, bh0, acc0, 0, 0, 0);
        acc0 = __builtin_amdgcn_mfma_f32_16x16x32_f16(ah, bl0, acc0, 0, 0, 0);
        acc1 = __builtin_amdgcn_mfma_f32_16x16x32_f16(ah, bh1, acc1, 0, 0, 0);
        acc1 = __builtin_amdgcn_mfma_f32_16x16x32_f16(al, bh1, acc1, 0, 0, 0);
        acc1 = __builtin_amdgcn_mfma_f32_16x16x32_f16(ah, bl1, acc1, 0, 0, 0);
    }

    int jcol = lane & 15;
    float t0 = tab[12480 + jcol],      t1 = tab[12480 + 16 + jcol];
    float w00 = g1W[jcol],      w01 = g1W[32 + jcol],      w02 = g1W[64 + jcol];
    float w10 = g1W[16 + jcol], w11 = g1W[48 + jcol],      w12 = g1W[80 + jcol];
#pragma unroll
    for (int r = 0; r < 4; ++r) {
        int node = n0 + q * 4 + r;
        if (node < n_end) {
            float4 xn = xpad[node];
            float dg = (float)ideg[node];
            float v0 = dg * t0 + xn.x * w00 + xn.y * w01 + xn.z * w02 + acc0[r];
            float v1 = dg * t1 + xn.x * w10 + xn.y * w11 + xn.z * w12 + acc1[r];
            xh1[node * 32 + jcol]      = (_Float16)v0;
            xh1[node * 32 + 16 + jcol] = (_Float16)v1;
        }
    }
}

// prop1 + fused xw2: 4 nodes/wave, 16 lanes/node, fp16x2 per lane.
// After the edge loop the 16-lane group holds h1[n][0:32]; apply relu(+g1b),
// then 32x32 matmul with g2W (columns preloaded) via in-group shfl.
__global__ __launch_bounds__(256, 4) void prop1_fused(
    const int* __restrict__ offs, const int* __restrict__ csr_row,
    const unsigned int* __restrict__ xhp, const float* __restrict__ dinv,
    const float* __restrict__ g1b, const float* __restrict__ g2W,
    unsigned int* __restrict__ Vhp) {
    int lane = threadIdx.x & 63;
    int l = lane & 15;
    float wlo[32], whi[32];
#pragma unroll
    for (int k = 0; k < 32; ++k) {
        wlo[k] = g2W[k * 32 + 2 * l];
        whi[k] = g2W[k * 32 + 2 * l + 1];
    }
    float blo = g1b[2 * l], bhi = g1b[2 * l + 1];

    int wid = blockIdx.x * 4 + (threadIdx.x >> 6);
    int n = wid * 4 + (lane >> 4);
    if (n >= NN) return;

    int e0 = offs[n], e1 = offs[n + 1];
    float s0l = 0.f, s0h = 0.f, s1l = 0.f, s1h = 0.f;
    int e = e0;
    for (; e + 1 < e1; e += 2) {
        int r0 = csr_row[e], r1 = csr_row[e + 1];
        float d0 = dinv[r0], d1 = dinv[r1];
        half2v p0 = __builtin_bit_cast(half2v, xhp[r0 * 16 + l]);
        half2v p1 = __builtin_bit_cast(half2v, xhp[r1 * 16 + l]);
        s0l += (float)p0.x * d0; s0h += (float)p0.y * d0;
        s1l += (float)p1.x * d1; s1h += (float)p1.y * d1;
    }
    if (e < e1) {
        int r = csr_row[e];
        float d = dinv[r];
        half2v p = __builtin_bit_cast(half2v, xhp[r * 16 + l]);
        s0l += (float)p.x * d; s0h += (float)p.y * d;
    }
    float di = dinv[n];
    half2v pn = __builtin_bit_cast(half2v, xhp[n * 16 + l]);
    float h1l = di * (s0l + s1l) + di * di * (float)pn.x;
    float h1h = di * (s0h + s1h) + di * di * (float)pn.y;
    float hl = fmaxf(h1l + blo, 0.f);
    float hh = fmaxf(h1h + bhi, 0.f);

    float al = 0.f, ah = 0.f;
    int base = lane & 48;
#pragma unroll
    for (int m = 0; m < 16; ++m) {
        float xl = __shfl(hl, base + m, 64);
        float xh2 = __shfl(hh, base + m, 64);
        al += xl * wlo[2 * m] + xh2 * wlo[2 * m + 1];
        ah += xl * whi[2 * m] + xh2 * whi[2 * m + 1];
    }
    half2v o = {(_Float16)al, (_Float16)ah};
    Vhp[n * 16 + l] = __builtin_bit_cast(unsigned int, o);
}

// prop2: same 4-node/wave gather structure, writes fp16 h2 (pre-bias).
__global__ __launch_bounds__(256, 4) void prop2_plain(
    const int* __restrict__ offs, const int* __restrict__ csr_row,
    const unsigned int* __restrict__ xhp, const float* __restrict__ dinv,
    unsigned int* __restrict__ outp) {
    int lane = threadIdx.x & 63;
    int l = lane & 15;
    int wid = blockIdx.x * 4 + (threadIdx.x >> 6);
    int n = wid * 4 + (lane >> 4);
    if (n >= NN) return;

    int e0 = offs[n], e1 = offs[n + 1];
    float s0l = 0.f, s0h = 0.f, s1l = 0.f, s1h = 0.f;
    int e = e0;
    for (; e + 1 < e1; e += 2) {
        int r0 = csr_row[e], r1 = csr_row[e + 1];
        float d0 = dinv[r0], d1 = dinv[r1];
        half2v p0 = __builtin_bit_cast(half2v, xhp[r0 * 16 + l]);
        half2v p1 = __builtin_bit_cast(half2v, xhp[r1 * 16 + l]);
        s0l += (float)p0.x * d0; s0h += (float)p0.y * d0;
        s1l += (float)p1.x * d1; s1h += (float)p1.y * d1;
    }
    if (e < e1) {
        int r = csr_row[e];
        float d = dinv[r];
        half2v p = __builtin_bit_cast(half2v, xhp[r * 16 + l]);
        s0l += (float)p.x * d; s0h += (float)p.y * d;
    }
    float di = dinv[n];
    half2v pn = __builtin_bit_cast(half2v, xhp[n * 16 + l]);
    half2v o = {(_Float16)(di * (s0l + s1l) + di * di * (float)pn.x),
                (_Float16)(di * (s0h + s1h) + di * di * (float)pn.y)};
    outp[n * 16 + l] = __builtin_bit_cast(unsigned int, o);
}

__global__ void pool_seg(const _Float16* __restrict__ h2, const float* __restrict__ g2b,
                         const int* __restrict__ batch, float* __restrict__ pooled,
                         float* __restrict__ counts) {
    int grp = threadIdx.x >> 5, j = threadIdx.x & 31;
    int base = (blockIdx.x * 8 + grp) * 64;
    if (base >= NN) return;
    float bj = g2b[j];
    float acc = 0.f, cnt = 0.f;
    int curg = -1;
    int lim = base + 64;
    if (lim > NN) lim = NN;
    for (int n = base; n < lim; ++n) {
        int g = batch[n];
        if (g != curg) {
            if (curg >= 0) {
                atomicAdd(&pooled[curg * 32 + j], acc);
                if (j == 0) atomicAdd(&counts[curg], cnt);
            }
            curg = g; acc = 0.f; cnt = 0.f;
        }
        acc += fmaxf((float)h2[n * 32 + j] + bj, 0.f);
        cnt += 1.f;
    }
    if (curg >= 0) {
        atomicAdd(&pooled[curg * 32 + j], acc);
        if (j == 0) atomicAdd(&counts[curg], cnt);
    }
}

__global__ void final_kernel(const float* __restrict__ pooled, const float* __restrict__ counts,
                             const float* __restrict__ clsW, const float* __restrict__ clsb,
                             float* __restrict__ out) {
    int tid = threadIdx.x;
    if (tid >= GG * CC) return;
    int g = tid / CC, cc = tid % CC;
    float inv = 1.0f / fmaxf(counts[g], 1.0f);
    float s = clsb[cc];
    for (int j = 0; j < 32; ++j) s += (pooled[g * 32 + j] * inv) * clsW[j * CC + cc];
    out[g * CC + cc] = s;
}

extern "C" void kernel_launch(void* const* d_in, const int* in_sizes, int n_in,
                              void* d_out, int out_size, void* d_ws, size_t ws_size,
                              hipStream_t stream) {
    const float* x     = (const float*)d_in[0];
    const int*   ei    = (const int*)d_in[1];
    const int*   batch = (const int*)d_in[2];
    const float* fW    = (const float*)d_in[3];
    const float* fb    = (const float*)d_in[4];
    const float* W1    = (const float*)d_in[5];
    const float* b1    = (const float*)d_in[6];
    const float* W2    = (const float*)d_in[7];
    const float* b2    = (const float*)d_in[8];
    const float* g1W   = (const float*)d_in[9];
    const float* g1b   = (const float*)d_in[10];
    const float* g2W   = (const float*)d_in[11];
    const float* g2b   = (const float*)d_in[12];
    const float* clsW  = (const float*)d_in[13];
    const float* clsb  = (const float*)d_in[14];
    float* out = (float*)d_out;

    float4*         xpad    = (float4*)d_ws;                       // 1.6 MB
    unsigned int*   agg     = (unsigned int*)(xpad + NN);          // 32 MB
    int*            csr_row = (int*)(agg + (size_t)STRIP * 320);   // 6.4 MB
    unsigned int*   part    = (unsigned int*)(csr_row + NE);       // 6.4 MB
    int*            mat     = (int*)(part + NE);                   // 156 KB
    int*            msum    = mat + MTOT;
    int*            ideg    = msum + 256;
    int*            offs    = ideg + NN;
    float*          dinv    = (float*)(offs + NN + 1);
    float*          tab     = dinv + NN;
    _Float16*       Mfrag   = (_Float16*)(tab + 16384);            // 40 KB
    _Float16*       xh1     = Mfrag + 20480;                       // 6.4 MB
    unsigned int*   Vhp     = (unsigned int*)(xh1 + (size_t)NN * 32);   // 6.4 MB
    unsigned int*   h2p     = Vhp + (size_t)NN * 16;               // 6.4 MB
    float*          pooled  = (float*)(h2p + (size_t)NN * 16);
    float*          counts  = pooled + GG * 32;

    const int propBlocks = (NN + 15) / 16;   // 16 nodes/block (4 waves x 4 nodes)

    zero_f<<<(GG * 33 + 255) / 256, 256, 0, stream>>>(pooled, GG * 33);
    precompute_small<<<10, 1024, 0, stream>>>(fW, fb, W1, b1, W2, b2, g1W, tab);
    mfrag_kernel<<<10, 256, 0, stream>>>(tab, Mfrag);

    bucket_hist<<<PBLK, 256, 0, stream>>>(ei, mat);
    scan_m1<<<MSB, 256, 0, stream>>>(mat, msum);
    scan_m2<<<1, 256, 0, stream>>>(msum);
    scan_m3<<<MSB, 256, 0, stream>>>(mat, msum);
    bucket_scatter<<<PBLK, 256, 0, stream>>>(ei, mat, part);
    bucket_build<<<NB, 256, 0, stream>>>(part, mat, x, csr_row, ideg, offs, dinv, xpad);

    for (int s = 0; s < NN / STRIP; ++s) {
        int ns = s * STRIP, ne2 = ns + STRIP;
        edgeconv_fused<<<2048, 256, 0, stream>>>(xpad, offs, csr_row, tab, agg, ns, ne2);
        int foldWaves = (STRIP + 15) / 16;
        fold_mfma<<<(foldWaves + 3) / 4, 256, 0, stream>>>(agg, Mfrag, xpad, ideg, tab, g1W,
                                                           xh1, ns, ne2);
    }

    prop1_fused<<<propBlocks, 256, 0, stream>>>(offs, csr_row, (const unsigned int*)xh1,
                                                dinv, g1b, g2W, Vhp);
    prop2_plain<<<propBlocks, 256, 0, stream>>>(offs, csr_row, Vhp, dinv, h2p);
    pool_seg<<<(NN + 511) / 512, 256, 0, stream>>>((const _Float16*)h2p, g2b, batch,
                                                   pooled, counts);
    final_kernel<<<1, 640, 0, stream>>>(pooled, counts, clsW, clsb, out);
}

// Round 14
// 433.990 us; speedup vs baseline: 1.3494x; 1.0983x over previous
//
#include <hip/hip_runtime.h>

#define NN 100000
#define NE 1600000
#define HH 32
#define CC 10
#define GG 64
#define STRIP 25000
#define NB 391
#define PBLK 100
#define ECH 16000
#define MTOT (NB * PBLK)
#define MSB ((MTOT + 255) / 256)

typedef _Float16 half8 __attribute__((ext_vector_type(8)));
typedef _Float16 half2v __attribute__((ext_vector_type(2)));
typedef float f32x4 __attribute__((ext_vector_type(4)));

__global__ void zero_f(float* p, int n) {
    int i = blockIdx.x * 256 + threadIdx.x;
    if (i < n) p[i] = 0.0f;
}

__global__ void precompute_small(const float* __restrict__ fW, const float* __restrict__ fb,
                                 const float* __restrict__ W1, const float* __restrict__ b1,
                                 const float* __restrict__ W2, const float* __restrict__ b2,
                                 const float* __restrict__ g1W, float* __restrict__ tab) {
    int c = blockIdx.x;
    int k = threadIdx.x >> 5;
    int j = threadIdx.x & 31;
    float m = 0.f;
    for (int mm = 0; mm < 32; ++mm)
        m += W2[k * 32 + mm] * g1W[(3 + 32 * c + mm) * 32 + j];
    tab[2240 + c * 1024 + k * 32 + j] = m;

    if (k < 3) {
        float a = 0.f, b = 0.f;
        for (int i = 0; i < 32; ++i) {
            float w = fW[c * 96 + k * 32 + i];
            a += w * W1[i * 32 + j];
            b += w * W1[(32 + i) * 32 + j];
        }
        tab[c * 96 + k * 32 + j] = a;
        tab[960 + c * 96 + k * 32 + j] = b;
    } else if (k == 3) {
        float h = b1[j];
        for (int i = 0; i < 32; ++i)
            h += fb[c * 32 + i] * (W1[i * 32 + j] + W1[(32 + i) * 32 + j]);
        tab[1920 + c * 32 + j] = h;
    } else if (k == 4 && c == 0) {
        float t = 0.f;
        for (int cc2 = 0; cc2 < CC; ++cc2)
            for (int mm = 0; mm < 32; ++mm)
                t += b2[mm] * g1W[(3 + 32 * cc2 + mm) * 32 + j];
        tab[12480 + j] = t;
    }
}

// B-fragments of Mflat[320][32], plain fp16. 20 sets (kc 0..9, jtile 0..1).
__global__ void mfrag_kernel(const float* __restrict__ tab, _Float16* __restrict__ Mfrag) {
    int gid = blockIdx.x * 256 + threadIdx.x;   // [0, 1280)
    if (gid >= 1280) return;
    int set = gid >> 6, l = gid & 63;
    int kc = set >> 1, jt = set & 1;
    int j = jt * 16 + (l & 15);
    int kbase = kc * 32 + (l >> 4) * 8;
#pragma unroll
    for (int i = 0; i < 8; ++i)
        Mfrag[gid * 8 + i] = (_Float16)tab[2240 + (kbase + i) * 32 + j];
}

// ---- atomic-free CSR build ----
__global__ void bucket_hist(const int* __restrict__ ei, int* __restrict__ mat) {
    __shared__ int h[NB];
    int blk = blockIdx.x, tid = threadIdx.x;
    for (int i = tid; i < NB; i += 256) h[i] = 0;
    __syncthreads();
    int base = blk * ECH;
    for (int k = tid; k < ECH; k += 256)
        atomicAdd(&h[ei[NE + base + k] >> 8], 1);
    __syncthreads();
    for (int i = tid; i < NB; i += 256) mat[i * PBLK + blk] = h[i];
}

__global__ void scan_m1(const int* __restrict__ mat, int* __restrict__ msum) {
    __shared__ int sh[256];
    int b = blockIdx.x, t = threadIdx.x;
    int i = b * 256 + t;
    sh[t] = (i < MTOT) ? mat[i] : 0;
    __syncthreads();
    for (int off = 128; off > 0; off >>= 1) {
        if (t < off) sh[t] += sh[t + off];
        __syncthreads();
    }
    if (t == 0) msum[b] = sh[0];
}

__global__ void scan_m2(int* __restrict__ msum) {
    __shared__ int sh[256];
    int t = threadIdx.x;
    int v = (t < MSB) ? msum[t] : 0;
    sh[t] = v;
    __syncthreads();
    for (int off = 1; off < 256; off <<= 1) {
        int add = (t >= off) ? sh[t - off] : 0;
        __syncthreads();
        sh[t] += add;
        __syncthreads();
    }
    if (t < MSB) msum[t] = sh[t] - v;
}

__global__ void scan_m3(int* __restrict__ mat, const int* __restrict__ msum) {
    __shared__ int sh[256];
    int b = blockIdx.x, t = threadIdx.x;
    int i = b * 256 + t;
    int v = (i < MTOT) ? mat[i] : 0;
    sh[t] = v;
    __syncthreads();
    for (int off = 1; off < 256; off <<= 1) {
        int add = (t >= off) ? sh[t - off] : 0;
        __syncthreads();
        sh[t] += add;
        __syncthreads();
    }
    if (i < MTOT) mat[i] = sh[t] - v + msum[b];
}

__global__ void bucket_scatter(const int* __restrict__ ei, const int* __restrict__ mat,
                               unsigned int* __restrict__ part) {
    __shared__ int bas[NB];
    __shared__ int cur[NB];
    int blk = blockIdx.x, tid = threadIdx.x;
    for (int i = tid; i < NB; i += 256) { bas[i] = mat[i * PBLK + blk]; cur[i] = 0; }
    __syncthreads();
    int base = blk * ECH;
    for (int k = tid; k < ECH; k += 256) {
        int e = base + k;
        int r = ei[e];
        int c = ei[NE + e];
        int b = c >> 8;
        int local = atomicAdd(&cur[b], 1);
        part[bas[b] + local] = (unsigned)r | ((unsigned)(c & 255) << 24);
    }
}

__global__ void bucket_build(const unsigned int* __restrict__ part, const int* __restrict__ mat,
                             const float* __restrict__ x, int* __restrict__ csr_row,
                             int* __restrict__ ideg, int* __restrict__ offs,
                             float* __restrict__ dinv, float4* __restrict__ xpad) {
    __shared__ int lh[256];
    __shared__ int lex[256];
    __shared__ int cur[256];
    int b = blockIdx.x, tid = threadIdx.x;
    int ebase = mat[b * PBLK];
    int eend = (b == NB - 1) ? NE : mat[(b + 1) * PBLK];
    int m = eend - ebase;
    lh[tid] = 0;
    __syncthreads();
    for (int k = tid; k < m; k += 256) {
        unsigned v = part[ebase + k];
        atomicAdd(&lh[v >> 24], 1);
    }
    __syncthreads();
    int cnt = lh[tid];
    lex[tid] = cnt;
    __syncthreads();
    for (int off = 1; off < 256; off <<= 1) {
        int v = (tid >= off) ? lex[tid - off] : 0;
        __syncthreads();
        lex[tid] += v;
        __syncthreads();
    }
    int excl = lex[tid] - cnt;
    lex[tid] = excl;
    cur[tid] = 0;
    int n = b * 256 + tid;
    if (n < NN) {
        ideg[n] = cnt;
        offs[n] = ebase + excl;
        float di = rsqrtf((float)cnt + 1.0f);
        dinv[n] = di;
        xpad[n] = make_float4(x[n * 3], x[n * 3 + 1], x[n * 3 + 2], di);
    }
    if (b == 0 && tid == 0) offs[NN] = NE;
    __syncthreads();
    for (int k = tid; k < m; k += 256) {
        unsigned v = part[ebase + k];
        int cl = (int)(v >> 24);
        int r = (int)(v & 0x00FFFFFFu);
        int local = atomicAdd(&cur[cl], 1);
        csr_row[ebase + lex[cl] + local] = r;
    }
}

__device__ __forceinline__ float bcast_lane(float v, int t) {
    return __uint_as_float(__builtin_amdgcn_readlane(__float_as_uint(v), (unsigned)t));
}

// Edge phase: one node per wave; writes agg as plain fp16.
__global__ __launch_bounds__(256, 8) void edgeconv_fused(
    const float4* __restrict__ xpad, const int* __restrict__ offs,
    const int* __restrict__ csr_row, const float* __restrict__ tab,
    _Float16* __restrict__ aggh, int n_start, int n_end) {
    int lane = threadIdx.x & 63;
    int j = lane & 31;
    int half = lane >> 5;
    int c0 = half * 5;

    float A0[5], A1[5], A2[5], B0[5], B1[5], B2[5], hb[5];
#pragma unroll
    for (int i = 0; i < 5; ++i) {
        int cb = (c0 + i) * 96;
        A0[i] = tab[cb + j];       A1[i] = tab[cb + 32 + j];       A2[i] = tab[cb + 64 + j];
        B0[i] = tab[960 + cb + j]; B1[i] = tab[960 + cb + 32 + j]; B2[i] = tab[960 + cb + 64 + j];
        hb[i] = tab[1920 + (c0 + i) * 32 + j];
    }

    int wid = blockIdx.x * 4 + (threadIdx.x >> 6);
    const int wstride = gridDim.x * 4;

    for (int n = n_start + wid; n < n_end; n += wstride) {
        float4 xn = xpad[n];
        float va[5], acc[5];
#pragma unroll
        for (int i = 0; i < 5; ++i) {
            va[i] = hb[i] + xn.x * B0[i] + xn.y * B1[i] + xn.z * B2[i];
            acc[i] = 0.f;
        }
        int e0 = offs[n], e1 = offs[n + 1];
        for (int base = e0; base < e1; base += 64) {
            int ee = base + lane;
            int r = (ee < e1) ? csr_row[ee] : 0;
            float4 q = xpad[r];
            int cnt2 = e1 - base;
            if (cnt2 > 64) cnt2 = 64;
            int t = 0;
            for (; t + 1 < cnt2; t += 2) {
                float px0 = bcast_lane(q.x, t),     py0 = bcast_lane(q.y, t),     pz0 = bcast_lane(q.z, t);
                float px1 = bcast_lane(q.x, t + 1), py1 = bcast_lane(q.y, t + 1), pz1 = bcast_lane(q.z, t + 1);
#pragma unroll
                for (int i = 0; i < 5; ++i)
                    acc[i] += fmaxf(va[i] + px0 * A0[i] + py0 * A1[i] + pz0 * A2[i], 0.f);
#pragma unroll
                for (int i = 0; i < 5; ++i)
                    acc[i] += fmaxf(va[i] + px1 * A0[i] + py1 * A1[i] + pz1 * A2[i], 0.f);
            }
            if (t < cnt2) {
                float px = bcast_lane(q.x, t), py = bcast_lane(q.y, t), pz = bcast_lane(q.z, t);
#pragma unroll
                for (int i = 0; i < 5; ++i)
                    acc[i] += fmaxf(va[i] + px * A0[i] + py * A1[i] + pz * A2[i], 0.f);
            }
        }
        _Float16* arow = aggh + (size_t)(n - n_start) * 320 + half * 160 + j;
#pragma unroll
        for (int i = 0; i < 5; ++i) arow[i * 32] = (_Float16)acc[i];
    }
}

// Fold via MFMA (plain fp16, 2 MFMA/kc) + fused xw1-init; writes y1 = h*dinv fp16.
__global__ __launch_bounds__(256) void fold_mfma(
    const _Float16* __restrict__ aggh, const _Float16* __restrict__ MfragG,
    const float4* __restrict__ xpad, const int* __restrict__ ideg,
    const float* __restrict__ tab, const float* __restrict__ g1W,
    _Float16* __restrict__ y1, int n_start, int n_end) {
    __shared__ _Float16 Mf[10240];
    {
        const uint4* src = (const uint4*)MfragG;
        uint4* dst = (uint4*)Mf;
        for (int i = threadIdx.x; i < 1280; i += 256) dst[i] = src[i];
    }
    __syncthreads();

    int wave = blockIdx.x * 4 + (threadIdx.x >> 6);
    int lane = threadIdx.x & 63;
    int n0 = n_start + wave * 16;
    if (n0 >= n_end) return;

    int m = lane & 15, q = lane >> 4;
    int arow_n = n0 + m;
    bool rowok = arow_n < n_end;
    const _Float16* arow = aggh + (size_t)(arow_n - n_start) * 320 + q * 8;

    const half8* mf = (const half8*)Mf;
    f32x4 acc0 = {0.f, 0.f, 0.f, 0.f};
    f32x4 acc1 = {0.f, 0.f, 0.f, 0.f};

    for (int kc = 0; kc < 10; ++kc) {
        half8 a;
        if (rowok) a = *(const half8*)(arow + kc * 32);
        else {
#pragma unroll
            for (int i = 0; i < 8; ++i) a[i] = (_Float16)0.f;
        }
        half8 b0 = mf[(kc * 2 + 0) * 64 + lane];
        half8 b1 = mf[(kc * 2 + 1) * 64 + lane];
        acc0 = __builtin_amdgcn_mfma_f32_16x16x32_f16(a, b0, acc0, 0, 0, 0);
        acc1 = __builtin_amdgcn_mfma_f32_16x16x32_f16(a, b1, acc1, 0, 0, 0);
    }

    int jcol = lane & 15;
    float t0 = tab[12480 + jcol],      t1 = tab[12480 + 16 + jcol];
    float w00 = g1W[jcol],      w01 = g1W[32 + jcol],      w02 = g1W[64 + jcol];
    float w10 = g1W[16 + jcol], w11 = g1W[48 + jcol],      w12 = g1W[80 + jcol];
#pragma unroll
    for (int r = 0; r < 4; ++r) {
        int node = n0 + q * 4 + r;
        if (node < n_end) {
            float4 xn = xpad[node];
            float dg = (float)ideg[node];
            float v0 = dg * t0 + xn.x * w00 + xn.y * w01 + xn.z * w02 + acc0[r];
            float v1 = dg * t1 + xn.x * w10 + xn.y * w11 + xn.z * w12 + acc1[r];
            y1[node * 32 + jcol]      = (_Float16)(v0 * xn.w);   // pre-scaled by dinv
            y1[node * 32 + 16 + jcol] = (_Float16)(v1 * xn.w);
        }
    }
}

// prop1 + fused xw2: 4 nodes/wave, 16 lanes/node, y-prescaled input (no dinv gather).
// h1 = di*(sum y1[r] + y1[n]); Vh stored pre-scaled: y2 = (relu(h1+b1)@g2W)*di.
__global__ __launch_bounds__(256, 8) void prop1_fused(
    const int* __restrict__ offs, const int* __restrict__ csr_row,
    const unsigned int* __restrict__ y1p, const float* __restrict__ dinv,
    const float* __restrict__ g1b, const float* __restrict__ g2W,
    unsigned int* __restrict__ y2p) {
    __shared__ float g2s[1024];
    for (int i = threadIdx.x; i < 1024; i += 256) g2s[i] = g2W[i];
    __syncthreads();

    int lane = threadIdx.x & 63;
    int l = lane & 15;
    int wid = blockIdx.x * 4 + (threadIdx.x >> 6);
    int n = wid * 4 + (lane >> 4);
    if (n >= NN) return;

    int e0 = offs[n], e1 = offs[n + 1];
    float s0l = 0.f, s0h = 0.f, s1l = 0.f, s1h = 0.f;
    float s2l = 0.f, s2h = 0.f, s3l = 0.f, s3h = 0.f;
    int e = e0;
    for (; e + 3 < e1; e += 4) {
        int r0 = csr_row[e], r1 = csr_row[e + 1], r2 = csr_row[e + 2], r3 = csr_row[e + 3];
        half2v p0 = __builtin_bit_cast(half2v, y1p[r0 * 16 + l]);
        half2v p1 = __builtin_bit_cast(half2v, y1p[r1 * 16 + l]);
        half2v p2 = __builtin_bit_cast(half2v, y1p[r2 * 16 + l]);
        half2v p3 = __builtin_bit_cast(half2v, y1p[r3 * 16 + l]);
        s0l += (float)p0.x; s0h += (float)p0.y;
        s1l += (float)p1.x; s1h += (float)p1.y;
        s2l += (float)p2.x; s2h += (float)p2.y;
        s3l += (float)p3.x; s3h += (float)p3.y;
    }
    for (; e < e1; ++e) {
        int r = csr_row[e];
        half2v p = __builtin_bit_cast(half2v, y1p[r * 16 + l]);
        s0l += (float)p.x; s0h += (float)p.y;
    }
    float di = dinv[n];
    half2v pn = __builtin_bit_cast(half2v, y1p[n * 16 + l]);
    float h1l = di * (s0l + s1l + s2l + s3l + (float)pn.x);
    float h1h = di * (s0h + s1h + s2h + s3h + (float)pn.y);
    float hl = fmaxf(h1l + g1b[2 * l], 0.f);
    float hh = fmaxf(h1h + g1b[2 * l + 1], 0.f);

    float al = 0.f, ah = 0.f;
    int base = lane & 48;
#pragma unroll
    for (int m = 0; m < 16; ++m) {
        float xl = __shfl(hl, base + m, 64);
        float xh2 = __shfl(hh, base + m, 64);
        al += xl * g2s[(2 * m) * 32 + 2 * l] + xh2 * g2s[(2 * m + 1) * 32 + 2 * l];
        ah += xl * g2s[(2 * m) * 32 + 2 * l + 1] + xh2 * g2s[(2 * m + 1) * 32 + 2 * l + 1];
    }
    half2v o = {(_Float16)(al * di), (_Float16)(ah * di)};
    y2p[n * 16 + l] = __builtin_bit_cast(unsigned int, o);
}

// prop2: same structure; h2 = di*(sum y2[r] + y2[n]); stored fp16 (pre-bias).
__global__ __launch_bounds__(256, 8) void prop2_plain(
    const int* __restrict__ offs, const int* __restrict__ csr_row,
    const unsigned int* __restrict__ y2p, const float* __restrict__ dinv,
    unsigned int* __restrict__ outp) {
    int lane = threadIdx.x & 63;
    int l = lane & 15;
    int wid = blockIdx.x * 4 + (threadIdx.x >> 6);
    int n = wid * 4 + (lane >> 4);
    if (n >= NN) return;

    int e0 = offs[n], e1 = offs[n + 1];
    float s0l = 0.f, s0h = 0.f, s1l = 0.f, s1h = 0.f;
    float s2l = 0.f, s2h = 0.f, s3l = 0.f, s3h = 0.f;
    int e = e0;
    for (; e + 3 < e1; e += 4) {
        int r0 = csr_row[e], r1 = csr_row[e + 1], r2 = csr_row[e + 2], r3 = csr_row[e + 3];
        half2v p0 = __builtin_bit_cast(half2v, y2p[r0 * 16 + l]);
        half2v p1 = __builtin_bit_cast(half2v, y2p[r1 * 16 + l]);
        half2v p2 = __builtin_bit_cast(half2v, y2p[r2 * 16 + l]);
        half2v p3 = __builtin_bit_cast(half2v, y2p[r3 * 16 + l]);
        s0l += (float)p0.x; s0h += (float)p0.y;
        s1l += (float)p1.x; s1h += (float)p1.y;
        s2l += (float)p2.x; s2h += (float)p2.y;
        s3l += (float)p3.x; s3h += (float)p3.y;
    }
    for (; e < e1; ++e) {
        int r = csr_row[e];
        half2v p = __builtin_bit_cast(half2v, y2p[r * 16 + l]);
        s0l += (float)p.x; s0h += (float)p.y;
    }
    float di = dinv[n];
    half2v pn = __builtin_bit_cast(half2v, y2p[n * 16 + l]);
    half2v o = {(_Float16)(di * (s0l + s1l + s2l + s3l + (float)pn.x)),
                (_Float16)(di * (s0h + s1h + s2h + s3h + (float)pn.y))};
    outp[n * 16 + l] = __builtin_bit_cast(unsigned int, o);
}

__global__ void pool_seg(const _Float16* __restrict__ h2, const float* __restrict__ g2b,
                         const int* __restrict__ batch, float* __restrict__ pooled,
                         float* __restrict__ counts) {
    int grp = threadIdx.x >> 5, j = threadIdx.x & 31;
    int base = (blockIdx.x * 8 + grp) * 64;
    if (base >= NN) return;
    float bj = g2b[j];
    float acc = 0.f, cnt = 0.f;
    int curg = -1;
    int lim = base + 64;
    if (lim > NN) lim = NN;
    for (int n = base; n < lim; ++n) {
        int g = batch[n];
        if (g != curg) {
            if (curg >= 0) {
                atomicAdd(&pooled[curg * 32 + j], acc);
                if (j == 0) atomicAdd(&counts[curg], cnt);
            }
            curg = g; acc = 0.f; cnt = 0.f;
        }
        acc += fmaxf((float)h2[n * 32 + j] + bj, 0.f);
        cnt += 1.f;
    }
    if (curg >= 0) {
        atomicAdd(&pooled[curg * 32 + j], acc);
        if (j == 0) atomicAdd(&counts[curg], cnt);
    }
}

__global__ void final_kernel(const float* __restrict__ pooled, const float* __restrict__ counts,
                             const float* __restrict__ clsW, const float* __restrict__ clsb,
                             float* __restrict__ out) {
    int tid = threadIdx.x;
    if (tid >= GG * CC) return;
    int g = tid / CC, cc = tid % CC;
    float inv = 1.0f / fmaxf(counts[g], 1.0f);
    float s = clsb[cc];
    for (int j = 0; j < 32; ++j) s += (pooled[g * 32 + j] * inv) * clsW[j * CC + cc];
    out[g * CC + cc] = s;
}

extern "C" void kernel_launch(void* const* d_in, const int* in_sizes, int n_in,
                              void* d_out, int out_size, void* d_ws, size_t ws_size,
                              hipStream_t stream) {
    const float* x     = (const float*)d_in[0];
    const int*   ei    = (const int*)d_in[1];
    const int*   batch = (const int*)d_in[2];
    const float* fW    = (const float*)d_in[3];
    const float* fb    = (const float*)d_in[4];
    const float* W1    = (const float*)d_in[5];
    const float* b1    = (const float*)d_in[6];
    const float* W2    = (const float*)d_in[7];
    const float* b2    = (const float*)d_in[8];
    const float* g1W   = (const float*)d_in[9];
    const float* g1b   = (const float*)d_in[10];
    const float* g2W   = (const float*)d_in[11];
    const float* g2b   = (const float*)d_in[12];
    const float* clsW  = (const float*)d_in[13];
    const float* clsb  = (const float*)d_in[14];
    float* out = (float*)d_out;

    float4*         xpad    = (float4*)d_ws;                          // 1.6 MB
    _Float16*       aggh    = (_Float16*)(xpad + NN);                 // 16 MB
    int*            csr_row = (int*)(aggh + (size_t)STRIP * 320);     // 6.4 MB
    unsigned int*   part    = (unsigned int*)(csr_row + NE);          // 6.4 MB
    int*            mat     = (int*)(part + NE);
    int*            msum    = mat + MTOT;
    int*            ideg    = msum + 256;
    int*            offs    = ideg + NN;
    float*          dinv    = (float*)(offs + NN + 1);
    float*          tab     = dinv + NN;
    _Float16*       Mfrag   = (_Float16*)(tab + 16384);               // 20 KB
    _Float16*       y1      = Mfrag + 10240;                          // 6.4 MB
    unsigned int*   y2p     = (unsigned int*)(y1 + (size_t)NN * 32);  // 6.4 MB
    unsigned int*   h2p     = y2p + (size_t)NN * 16;                  // 6.4 MB
    float*          pooled  = (float*)(h2p + (size_t)NN * 16);
    float*          counts  = pooled + GG * 32;

    const int propBlocks = (NN + 15) / 16;

    zero_f<<<(GG * 33 + 255) / 256, 256, 0, stream>>>(pooled, GG * 33);
    precompute_small<<<10, 1024, 0, stream>>>(fW, fb, W1, b1, W2, b2, g1W, tab);
    mfrag_kernel<<<5, 256, 0, stream>>>(tab, Mfrag);

    bucket_hist<<<PBLK, 256, 0, stream>>>(ei, mat);
    scan_m1<<<MSB, 256, 0, stream>>>(mat, msum);
    scan_m2<<<1, 256, 0, stream>>>(msum);
    scan_m3<<<MSB, 256, 0, stream>>>(mat, msum);
    bucket_scatter<<<PBLK, 256, 0, stream>>>(ei, mat, part);
    bucket_build<<<NB, 256, 0, stream>>>(part, mat, x, csr_row, ideg, offs, dinv, xpad);

    for (int s = 0; s < NN / STRIP; ++s) {
        int ns = s * STRIP, ne2 = ns + STRIP;
        edgeconv_fused<<<2048, 256, 0, stream>>>(xpad, offs, csr_row, tab, aggh, ns, ne2);
        int foldWaves = (STRIP + 15) / 16;
        fold_mfma<<<(foldWaves + 3) / 4, 256, 0, stream>>>(aggh, Mfrag, xpad, ideg, tab, g1W,
                                                           y1, ns, ne2);
    }

    prop1_fused<<<propBlocks, 256, 0, stream>>>(offs, csr_row, (const unsigned int*)y1,
                                                dinv, g1b, g2W, y2p);
    prop2_plain<<<propBlocks, 256, 0, stream>>>(offs, csr_row, y2p, dinv, h2p);
    pool_seg<<<(NN + 511) / 512, 256, 0, stream>>>((const _Float16*)h2p, g2b, batch,
                                                   pooled, counts);
    final_kernel<<<1, 640, 0, stream>>>(pooled, counts, clsW, clsb, out);
}

// Round 15
// 399.688 us; speedup vs baseline: 1.4653x; 1.0858x over previous
//
#include <hip/hip_runtime.h>

#define NN 100000
#define NE 1600000
#define HH 32
#define CC 10
#define GG 64
#define NB 391
#define PBLK 100
#define ECH 16000
#define MTOT (NB * PBLK)
#define MSB ((MTOT + 255) / 256)

typedef _Float16 half8 __attribute__((ext_vector_type(8)));
typedef _Float16 half2v __attribute__((ext_vector_type(2)));
typedef float f32x4 __attribute__((ext_vector_type(4)));

__global__ void zero_f(float* p, int n) {
    int i = blockIdx.x * 256 + threadIdx.x;
    if (i < n) p[i] = 0.0f;
}

__global__ void precompute_small(const float* __restrict__ fW, const float* __restrict__ fb,
                                 const float* __restrict__ W1, const float* __restrict__ b1,
                                 const float* __restrict__ W2, const float* __restrict__ b2,
                                 const float* __restrict__ g1W, float* __restrict__ tab) {
    int c = blockIdx.x;
    int k = threadIdx.x >> 5;
    int j = threadIdx.x & 31;
    float m = 0.f;
    for (int mm = 0; mm < 32; ++mm)
        m += W2[k * 32 + mm] * g1W[(3 + 32 * c + mm) * 32 + j];
    tab[2240 + c * 1024 + k * 32 + j] = m;

    if (k < 3) {
        float a = 0.f, b = 0.f;
        for (int i = 0; i < 32; ++i) {
            float w = fW[c * 96 + k * 32 + i];
            a += w * W1[i * 32 + j];
            b += w * W1[(32 + i) * 32 + j];
        }
        tab[c * 96 + k * 32 + j] = a;
        tab[960 + c * 96 + k * 32 + j] = b;
    } else if (k == 3) {
        float h = b1[j];
        for (int i = 0; i < 32; ++i)
            h += fb[c * 32 + i] * (W1[i * 32 + j] + W1[(32 + i) * 32 + j]);
        tab[1920 + c * 32 + j] = h;
    } else if (k == 4 && c == 0) {
        float t = 0.f;
        for (int cc2 = 0; cc2 < CC; ++cc2)
            for (int mm = 0; mm < 32; ++mm)
                t += b2[mm] * g1W[(3 + 32 * cc2 + mm) * 32 + j];
        tab[12480 + j] = t;
    }
}

// B-fragments of Mflat[320][32], plain fp16. 20 sets (kc 0..9, jtile 0..1).
__global__ void mfrag_kernel(const float* __restrict__ tab, _Float16* __restrict__ Mfrag) {
    int gid = blockIdx.x * 256 + threadIdx.x;   // [0, 1280)
    if (gid >= 1280) return;
    int set = gid >> 6, l = gid & 63;
    int kc = set >> 1, jt = set & 1;
    int j = jt * 16 + (l & 15);
    int kbase = kc * 32 + (l >> 4) * 8;
#pragma unroll
    for (int i = 0; i < 8; ++i)
        Mfrag[gid * 8 + i] = (_Float16)tab[2240 + (kbase + i) * 32 + j];
}

// ---- atomic-free CSR build ----
__global__ void bucket_hist(const int* __restrict__ ei, int* __restrict__ mat) {
    __shared__ int h[NB];
    int blk = blockIdx.x, tid = threadIdx.x;
    for (int i = tid; i < NB; i += 256) h[i] = 0;
    __syncthreads();
    int base = blk * ECH;
    for (int k = tid; k < ECH; k += 256)
        atomicAdd(&h[ei[NE + base + k] >> 8], 1);
    __syncthreads();
    for (int i = tid; i < NB; i += 256) mat[i * PBLK + blk] = h[i];
}

__global__ void scan_m1(const int* __restrict__ mat, int* __restrict__ msum) {
    __shared__ int sh[256];
    int b = blockIdx.x, t = threadIdx.x;
    int i = b * 256 + t;
    sh[t] = (i < MTOT) ? mat[i] : 0;
    __syncthreads();
    for (int off = 128; off > 0; off >>= 1) {
        if (t < off) sh[t] += sh[t + off];
        __syncthreads();
    }
    if (t == 0) msum[b] = sh[0];
}

__global__ void scan_m2(int* __restrict__ msum) {
    __shared__ int sh[256];
    int t = threadIdx.x;
    int v = (t < MSB) ? msum[t] : 0;
    sh[t] = v;
    __syncthreads();
    for (int off = 1; off < 256; off <<= 1) {
        int add = (t >= off) ? sh[t - off] : 0;
        __syncthreads();
        sh[t] += add;
        __syncthreads();
    }
    if (t < MSB) msum[t] = sh[t] - v;
}

__global__ void scan_m3(int* __restrict__ mat, const int* __restrict__ msum) {
    __shared__ int sh[256];
    int b = blockIdx.x, t = threadIdx.x;
    int i = b * 256 + t;
    int v = (i < MTOT) ? mat[i] : 0;
    sh[t] = v;
    __syncthreads();
    for (int off = 1; off < 256; off <<= 1) {
        int add = (t >= off) ? sh[t - off] : 0;
        __syncthreads();
        sh[t] += add;
        __syncthreads();
    }
    if (i < MTOT) mat[i] = sh[t] - v + msum[b];
}

__global__ void bucket_scatter(const int* __restrict__ ei, const int* __restrict__ mat,
                               unsigned int* __restrict__ part) {
    __shared__ int bas[NB];
    __shared__ int cur[NB];
    int blk = blockIdx.x, tid = threadIdx.x;
    for (int i = tid; i < NB; i += 256) { bas[i] = mat[i * PBLK + blk]; cur[i] = 0; }
    __syncthreads();
    int base = blk * ECH;
    for (int k = tid; k < ECH; k += 256) {
        int e = base + k;
        int r = ei[e];
        int c = ei[NE + e];
        int b = c >> 8;
        int local = atomicAdd(&cur[b], 1);
        part[bas[b] + local] = (unsigned)r | ((unsigned)(c & 255) << 24);
    }
}

__global__ void bucket_build(const unsigned int* __restrict__ part, const int* __restrict__ mat,
                             const float* __restrict__ x, int* __restrict__ csr_row,
                             int* __restrict__ ideg, int* __restrict__ offs,
                             float* __restrict__ dinv, float4* __restrict__ xpad) {
    __shared__ int lh[256];
    __shared__ int lex[256];
    __shared__ int cur[256];
    int b = blockIdx.x, tid = threadIdx.x;
    int ebase = mat[b * PBLK];
    int eend = (b == NB - 1) ? NE : mat[(b + 1) * PBLK];
    int m = eend - ebase;
    lh[tid] = 0;
    __syncthreads();
    for (int k = tid; k < m; k += 256) {
        unsigned v = part[ebase + k];
        atomicAdd(&lh[v >> 24], 1);
    }
    __syncthreads();
    int cnt = lh[tid];
    lex[tid] = cnt;
    __syncthreads();
    for (int off = 1; off < 256; off <<= 1) {
        int v = (tid >= off) ? lex[tid - off] : 0;
        __syncthreads();
        lex[tid] += v;
        __syncthreads();
    }
    int excl = lex[tid] - cnt;
    lex[tid] = excl;
    cur[tid] = 0;
    int n = b * 256 + tid;
    if (n < NN) {
        ideg[n] = cnt;
        offs[n] = ebase + excl;
        float di = rsqrtf((float)cnt + 1.0f);
        dinv[n] = di;
        xpad[n] = make_float4(x[n * 3], x[n * 3 + 1], x[n * 3 + 2], di);
    }
    if (b == 0 && tid == 0) offs[NN] = NE;
    __syncthreads();
    for (int k = tid; k < m; k += 256) {
        unsigned v = part[ebase + k];
        int cl = (int)(v >> 24);
        int r = (int)(v & 0x00FFFFFFu);
        int local = atomicAdd(&cur[cl], 1);
        csr_row[ebase + lex[cl] + local] = r;
    }
}

__device__ __forceinline__ float bcast_lane(float v, int t) {
    return __uint_as_float(__builtin_amdgcn_readlane(__float_as_uint(v), (unsigned)t));
}

// Edge phase: one node per wave (grid-stride over all NN); writes agg fp16.
__global__ __launch_bounds__(256, 8) void edgeconv_fused(
    const float4* __restrict__ xpad, const int* __restrict__ offs,
    const int* __restrict__ csr_row, const float* __restrict__ tab,
    _Float16* __restrict__ aggh) {
    int lane = threadIdx.x & 63;
    int j = lane & 31;
    int half = lane >> 5;
    int c0 = half * 5;

    float A0[5], A1[5], A2[5], B0[5], B1[5], B2[5], hb[5];
#pragma unroll
    for (int i = 0; i < 5; ++i) {
        int cb = (c0 + i) * 96;
        A0[i] = tab[cb + j];       A1[i] = tab[cb + 32 + j];       A2[i] = tab[cb + 64 + j];
        B0[i] = tab[960 + cb + j]; B1[i] = tab[960 + cb + 32 + j]; B2[i] = tab[960 + cb + 64 + j];
        hb[i] = tab[1920 + (c0 + i) * 32 + j];
    }

    int wid = blockIdx.x * 4 + (threadIdx.x >> 6);
    const int wstride = gridDim.x * 4;

    for (int n = wid; n < NN; n += wstride) {
        float4 xn = xpad[n];
        float va[5], acc[5];
#pragma unroll
        for (int i = 0; i < 5; ++i) {
            va[i] = hb[i] + xn.x * B0[i] + xn.y * B1[i] + xn.z * B2[i];
            acc[i] = 0.f;
        }
        int e0 = offs[n], e1 = offs[n + 1];
        for (int base = e0; base < e1; base += 64) {
            int ee = base + lane;
            int r = (ee < e1) ? csr_row[ee] : 0;
            float4 q = xpad[r];
            int cnt2 = e1 - base;
            if (cnt2 > 64) cnt2 = 64;
            int t = 0;
            for (; t + 1 < cnt2; t += 2) {
                float px0 = bcast_lane(q.x, t),     py0 = bcast_lane(q.y, t),     pz0 = bcast_lane(q.z, t);
                float px1 = bcast_lane(q.x, t + 1), py1 = bcast_lane(q.y, t + 1), pz1 = bcast_lane(q.z, t + 1);
#pragma unroll
                for (int i = 0; i < 5; ++i)
                    acc[i] += fmaxf(va[i] + px0 * A0[i] + py0 * A1[i] + pz0 * A2[i], 0.f);
#pragma unroll
                for (int i = 0; i < 5; ++i)
                    acc[i] += fmaxf(va[i] + px1 * A0[i] + py1 * A1[i] + pz1 * A2[i], 0.f);
            }
            if (t < cnt2) {
                float px = bcast_lane(q.x, t), py = bcast_lane(q.y, t), pz = bcast_lane(q.z, t);
#pragma unroll
                for (int i = 0; i < 5; ++i)
                    acc[i] += fmaxf(va[i] + px * A0[i] + py * A1[i] + pz * A2[i], 0.f);
            }
        }
        _Float16* arow = aggh + (size_t)n * 320 + half * 160 + j;
#pragma unroll
        for (int i = 0; i < 5; ++i) arow[i * 32] = (_Float16)acc[i];
    }
}

// Fold via MFMA (plain fp16, 2 MFMA/kc) + fused xw1-init; writes y1 = h*dinv fp16.
__global__ __launch_bounds__(256) void fold_mfma(
    const _Float16* __restrict__ aggh, const _Float16* __restrict__ MfragG,
    const float4* __restrict__ xpad, const int* __restrict__ ideg,
    const float* __restrict__ tab, const float* __restrict__ g1W,
    _Float16* __restrict__ y1) {
    __shared__ _Float16 Mf[10240];
    {
        const uint4* src = (const uint4*)MfragG;
        uint4* dst = (uint4*)Mf;
        for (int i = threadIdx.x; i < 1280; i += 256) dst[i] = src[i];
    }
    __syncthreads();

    int wave = blockIdx.x * 4 + (threadIdx.x >> 6);
    int lane = threadIdx.x & 63;
    int n0 = wave * 16;
    if (n0 >= NN) return;

    int m = lane & 15, q = lane >> 4;
    int arow_n = n0 + m;
    bool rowok = arow_n < NN;
    const _Float16* arow = aggh + (size_t)arow_n * 320 + q * 8;

    const half8* mf = (const half8*)Mf;
    f32x4 acc0 = {0.f, 0.f, 0.f, 0.f};
    f32x4 acc1 = {0.f, 0.f, 0.f, 0.f};

    for (int kc = 0; kc < 10; ++kc) {
        half8 a;
        if (rowok) a = *(const half8*)(arow + kc * 32);
        else {
#pragma unroll
            for (int i = 0; i < 8; ++i) a[i] = (_Float16)0.f;
        }
        half8 b0 = mf[(kc * 2 + 0) * 64 + lane];
        half8 b1 = mf[(kc * 2 + 1) * 64 + lane];
        acc0 = __builtin_amdgcn_mfma_f32_16x16x32_f16(a, b0, acc0, 0, 0, 0);
        acc1 = __builtin_amdgcn_mfma_f32_16x16x32_f16(a, b1, acc1, 0, 0, 0);
    }

    int jcol = lane & 15;
    float t0 = tab[12480 + jcol],      t1 = tab[12480 + 16 + jcol];
    float w00 = g1W[jcol],      w01 = g1W[32 + jcol],      w02 = g1W[64 + jcol];
    float w10 = g1W[16 + jcol], w11 = g1W[48 + jcol],      w12 = g1W[80 + jcol];
#pragma unroll
    for (int r = 0; r < 4; ++r) {
        int node = n0 + q * 4 + r;
        if (node < NN) {
            float4 xn = xpad[node];
            float dg = (float)ideg[node];
            float v0 = dg * t0 + xn.x * w00 + xn.y * w01 + xn.z * w02 + acc0[r];
            float v1 = dg * t1 + xn.x * w10 + xn.y * w11 + xn.z * w12 + acc1[r];
            y1[node * 32 + jcol]      = (_Float16)(v0 * xn.w);
            y1[node * 32 + 16 + jcol] = (_Float16)(v1 * xn.w);
        }
    }
}

// prop1 + fused xw2: 4 nodes/wave, 16 lanes/node, unroll-8 gathers.
__global__ __launch_bounds__(256, 8) void prop1_fused(
    const int* __restrict__ offs, const int* __restrict__ csr_row,
    const unsigned int* __restrict__ y1p, const float* __restrict__ dinv,
    const float* __restrict__ g1b, const float* __restrict__ g2W,
    unsigned int* __restrict__ y2p) {
    __shared__ float g2s[1024];
    for (int i = threadIdx.x; i < 1024; i += 256) g2s[i] = g2W[i];
    __syncthreads();

    int lane = threadIdx.x & 63;
    int l = lane & 15;
    int wid = blockIdx.x * 4 + (threadIdx.x >> 6);
    int n = wid * 4 + (lane >> 4);
    if (n >= NN) return;

    int e0 = offs[n], e1 = offs[n + 1];
    float sAl = 0.f, sAh = 0.f, sBl = 0.f, sBh = 0.f;
    int e = e0;
    for (; e + 7 < e1; e += 8) {
        int r[8];
#pragma unroll
        for (int u = 0; u < 8; ++u) r[u] = csr_row[e + u];
        half2v p[8];
#pragma unroll
        for (int u = 0; u < 8; ++u) p[u] = __builtin_bit_cast(half2v, y1p[r[u] * 16 + l]);
#pragma unroll
        for (int u = 0; u < 8; u += 2) {
            sAl += (float)p[u].x;     sAh += (float)p[u].y;
            sBl += (float)p[u + 1].x; sBh += (float)p[u + 1].y;
        }
    }
    for (; e < e1; ++e) {
        int r = csr_row[e];
        half2v p = __builtin_bit_cast(half2v, y1p[r * 16 + l]);
        sAl += (float)p.x; sAh += (float)p.y;
    }
    float di = dinv[n];
    half2v pn = __builtin_bit_cast(half2v, y1p[n * 16 + l]);
    float h1l = di * (sAl + sBl + (float)pn.x);
    float h1h = di * (sAh + sBh + (float)pn.y);
    float hl = fmaxf(h1l + g1b[2 * l], 0.f);
    float hh = fmaxf(h1h + g1b[2 * l + 1], 0.f);

    float al = 0.f, ah = 0.f;
    int base = lane & 48;
#pragma unroll
    for (int m = 0; m < 16; ++m) {
        float xl = __shfl(hl, base + m, 64);
        float xh2 = __shfl(hh, base + m, 64);
        al += xl * g2s[(2 * m) * 32 + 2 * l] + xh2 * g2s[(2 * m + 1) * 32 + 2 * l];
        ah += xl * g2s[(2 * m) * 32 + 2 * l + 1] + xh2 * g2s[(2 * m + 1) * 32 + 2 * l + 1];
    }
    half2v o = {(_Float16)(al * di), (_Float16)(ah * di)};
    y2p[n * 16 + l] = __builtin_bit_cast(unsigned int, o);
}

// prop2: same structure; h2 = di*(sum y2[r] + y2[n]); stored fp16 (pre-bias).
__global__ __launch_bounds__(256, 8) void prop2_plain(
    const int* __restrict__ offs, const int* __restrict__ csr_row,
    const unsigned int* __restrict__ y2p, const float* __restrict__ dinv,
    unsigned int* __restrict__ outp) {
    int lane = threadIdx.x & 63;
    int l = lane & 15;
    int wid = blockIdx.x * 4 + (threadIdx.x >> 6);
    int n = wid * 4 + (lane >> 4);
    if (n >= NN) return;

    int e0 = offs[n], e1 = offs[n + 1];
    float sAl = 0.f, sAh = 0.f, sBl = 0.f, sBh = 0.f;
    int e = e0;
    for (; e + 7 < e1; e += 8) {
        int r[8];
#pragma unroll
        for (int u = 0; u < 8; ++u) r[u] = csr_row[e + u];
        half2v p[8];
#pragma unroll
        for (int u = 0; u < 8; ++u) p[u] = __builtin_bit_cast(half2v, y2p[r[u] * 16 + l]);
#pragma unroll
        for (int u = 0; u < 8; u += 2) {
            sAl += (float)p[u].x;     sAh += (float)p[u].y;
            sBl += (float)p[u + 1].x; sBh += (float)p[u + 1].y;
        }
    }
    for (; e < e1; ++e) {
        int r = csr_row[e];
        half2v p = __builtin_bit_cast(half2v, y2p[r * 16 + l]);
        sAl += (float)p.x; sAh += (float)p.y;
    }
    float di = dinv[n];
    half2v pn = __builtin_bit_cast(half2v, y2p[n * 16 + l]);
    half2v o = {(_Float16)(di * (sAl + sBl + (float)pn.x)),
                (_Float16)(di * (sAh + sBh + (float)pn.y))};
    outp[n * 16 + l] = __builtin_bit_cast(unsigned int, o);
}

__global__ void pool_seg(const _Float16* __restrict__ h2, const float* __restrict__ g2b,
                         const int* __restrict__ batch, float* __restrict__ pooled,
                         float* __restrict__ counts) {
    int grp = threadIdx.x >> 5, j = threadIdx.x & 31;
    int base = (blockIdx.x * 8 + grp) * 64;
    if (base >= NN) return;
    float bj = g2b[j];
    float acc = 0.f, cnt = 0.f;
    int curg = -1;
    int lim = base + 64;
    if (lim > NN) lim = NN;
    for (int n = base; n < lim; ++n) {
        int g = batch[n];
        if (g != curg) {
            if (curg >= 0) {
                atomicAdd(&pooled[curg * 32 + j], acc);
                if (j == 0) atomicAdd(&counts[curg], cnt);
            }
            curg = g; acc = 0.f; cnt = 0.f;
        }
        acc += fmaxf((float)h2[n * 32 + j] + bj, 0.f);
        cnt += 1.f;
    }
    if (curg >= 0) {
        atomicAdd(&pooled[curg * 32 + j], acc);
        if (j == 0) atomicAdd(&counts[curg], cnt);
    }
}

__global__ void final_kernel(const float* __restrict__ pooled, const float* __restrict__ counts,
                             const float* __restrict__ clsW, const float* __restrict__ clsb,
                             float* __restrict__ out) {
    int tid = threadIdx.x;
    if (tid >= GG * CC) return;
    int g = tid / CC, cc = tid % CC;
    float inv = 1.0f / fmaxf(counts[g], 1.0f);
    float s = clsb[cc];
    for (int j = 0; j < 32; ++j) s += (pooled[g * 32 + j] * inv) * clsW[j * CC + cc];
    out[g * CC + cc] = s;
}

extern "C" void kernel_launch(void* const* d_in, const int* in_sizes, int n_in,
                              void* d_out, int out_size, void* d_ws, size_t ws_size,
                              hipStream_t stream) {
    const float* x     = (const float*)d_in[0];
    const int*   ei    = (const int*)d_in[1];
    const int*   batch = (const int*)d_in[2];
    const float* fW    = (const float*)d_in[3];
    const float* fb    = (const float*)d_in[4];
    const float* W1    = (const float*)d_in[5];
    const float* b1    = (const float*)d_in[6];
    const float* W2    = (const float*)d_in[7];
    const float* b2    = (const float*)d_in[8];
    const float* g1W   = (const float*)d_in[9];
    const float* g1b   = (const float*)d_in[10];
    const float* g2W   = (const float*)d_in[11];
    const float* g2b   = (const float*)d_in[12];
    const float* clsW  = (const float*)d_in[13];
    const float* clsb  = (const float*)d_in[14];
    float* out = (float*)d_out;

    float4*         xpad    = (float4*)d_ws;                          // 1.6 MB
    _Float16*       aggh    = (_Float16*)(xpad + NN);                 // 64 MB (full)
    unsigned int*   part    = (unsigned int*)aggh;                    // ALIAS: build-phase only
    int*            csr_row = (int*)(aggh + (size_t)NN * 320);        // 6.4 MB
    int*            mat     = (int*)(csr_row + NE);
    int*            msum    = mat + MTOT;
    int*            ideg    = msum + 256;
    int*            offs    = ideg + NN;
    float*          dinv    = (float*)(offs + NN + 1);
    float*          tab     = dinv + NN;
    _Float16*       Mfrag   = (_Float16*)(tab + 16384);               // 20 KB
    _Float16*       y1      = Mfrag + 10240;                          // 6.4 MB
    unsigned int*   y2p     = (unsigned int*)(y1 + (size_t)NN * 32);  // 6.4 MB
    unsigned int*   h2p     = y2p + (size_t)NN * 16;                  // 6.4 MB
    float*          pooled  = (float*)(h2p + (size_t)NN * 16);
    float*          counts  = pooled + GG * 32;

    const int propBlocks = (NN + 15) / 16;
    const int foldBlocks = ((NN + 15) / 16 + 3) / 4;

    zero_f<<<(GG * 33 + 255) / 256, 256, 0, stream>>>(pooled, GG * 33);
    precompute_small<<<10, 1024, 0, stream>>>(fW, fb, W1, b1, W2, b2, g1W, tab);
    mfrag_kernel<<<5, 256, 0, stream>>>(tab, Mfrag);

    bucket_hist<<<PBLK, 256, 0, stream>>>(ei, mat);
    scan_m1<<<MSB, 256, 0, stream>>>(mat, msum);
    scan_m2<<<1, 256, 0, stream>>>(msum);
    scan_m3<<<MSB, 256, 0, stream>>>(mat, msum);
    bucket_scatter<<<PBLK, 256, 0, stream>>>(ei, mat, part);
    bucket_build<<<NB, 256, 0, stream>>>(part, mat, x, csr_row, ideg, offs, dinv, xpad);

    edgeconv_fused<<<2048, 256, 0, stream>>>(xpad, offs, csr_row, tab, aggh);
    fold_mfma<<<foldBlocks, 256, 0, stream>>>(aggh, Mfrag, xpad, ideg, tab, g1W, y1);

    prop1_fused<<<propBlocks, 256, 0, stream>>>(offs, csr_row, (const unsigned int*)y1,
                                                dinv, g1b, g2W, y2p);
    prop2_plain<<<propBlocks, 256, 0, stream>>>(offs, csr_row, y2p, dinv, h2p);
    pool_seg<<<(NN + 511) / 512, 256, 0, stream>>>((const _Float16*)h2p, g2b, batch,
                                                   pooled, counts);
    final_kernel<<<1, 640, 0, stream>>>(pooled, counts, clsW, clsb, out);
}

// Round 16
// 391.539 us; speedup vs baseline: 1.4958x; 1.0208x over previous
//
#include <hip/hip_runtime.h>

#define NN 100000
#define NE 1600000
#define HH 32
#define CC 10
#define GG 64
#define NB 391
#define PBLK 100
#define ECH 16000
#define MTOT (NB * PBLK)
#define MSB ((MTOT + 255) / 256)

typedef _Float16 half8 __attribute__((ext_vector_type(8)));
typedef _Float16 half2v __attribute__((ext_vector_type(2)));
typedef float f32x4 __attribute__((ext_vector_type(4)));

__device__ __forceinline__ half2v bch(int v) { return __builtin_bit_cast(half2v, v); }

__global__ void zero_f(float* p, int n) {
    int i = blockIdx.x * 256 + threadIdx.x;
    if (i < n) p[i] = 0.0f;
}

__global__ void precompute_small(const float* __restrict__ fW, const float* __restrict__ fb,
                                 const float* __restrict__ W1, const float* __restrict__ b1,
                                 const float* __restrict__ W2, const float* __restrict__ b2,
                                 const float* __restrict__ g1W, float* __restrict__ tab) {
    int c = blockIdx.x;
    int k = threadIdx.x >> 5;
    int j = threadIdx.x & 31;
    float m = 0.f;
    for (int mm = 0; mm < 32; ++mm)
        m += W2[k * 32 + mm] * g1W[(3 + 32 * c + mm) * 32 + j];
    tab[2240 + c * 1024 + k * 32 + j] = m;

    if (k < 3) {
        float a = 0.f, b = 0.f;
        for (int i = 0; i < 32; ++i) {
            float w = fW[c * 96 + k * 32 + i];
            a += w * W1[i * 32 + j];
            b += w * W1[(32 + i) * 32 + j];
        }
        tab[c * 96 + k * 32 + j] = a;
        tab[960 + c * 96 + k * 32 + j] = b;
    } else if (k == 3) {
        float h = b1[j];
        for (int i = 0; i < 32; ++i)
            h += fb[c * 32 + i] * (W1[i * 32 + j] + W1[(32 + i) * 32 + j]);
        tab[1920 + c * 32 + j] = h;
    } else if (k == 4 && c == 0) {
        float t = 0.f;
        for (int cc2 = 0; cc2 < CC; ++cc2)
            for (int mm = 0; mm < 32; ++mm)
                t += b2[mm] * g1W[(3 + 32 * cc2 + mm) * 32 + j];
        tab[12480 + j] = t;
    }
}

// B-fragments of Mflat[320][32], plain fp16. 20 sets (kc 0..9, jtile 0..1).
__global__ void mfrag_kernel(const float* __restrict__ tab, _Float16* __restrict__ Mfrag) {
    int gid = blockIdx.x * 256 + threadIdx.x;   // [0, 1280)
    if (gid >= 1280) return;
    int set = gid >> 6, l = gid & 63;
    int kc = set >> 1, jt = set & 1;
    int j = jt * 16 + (l & 15);
    int kbase = kc * 32 + (l >> 4) * 8;
#pragma unroll
    for (int i = 0; i < 8; ++i)
        Mfrag[gid * 8 + i] = (_Float16)tab[2240 + (kbase + i) * 32 + j];
}

// ---- atomic-free CSR build ----
__global__ void bucket_hist(const int* __restrict__ ei, int* __restrict__ mat) {
    __shared__ int h[NB];
    int blk = blockIdx.x, tid = threadIdx.x;
    for (int i = tid; i < NB; i += 256) h[i] = 0;
    __syncthreads();
    int base = blk * ECH;
    for (int k = tid; k < ECH; k += 256)
        atomicAdd(&h[ei[NE + base + k] >> 8], 1);
    __syncthreads();
    for (int i = tid; i < NB; i += 256) mat[i * PBLK + blk] = h[i];
}

__global__ void scan_m1(const int* __restrict__ mat, int* __restrict__ msum) {
    __shared__ int sh[256];
    int b = blockIdx.x, t = threadIdx.x;
    int i = b * 256 + t;
    sh[t] = (i < MTOT) ? mat[i] : 0;
    __syncthreads();
    for (int off = 128; off > 0; off >>= 1) {
        if (t < off) sh[t] += sh[t + off];
        __syncthreads();
    }
    if (t == 0) msum[b] = sh[0];
}

__global__ void scan_m2(int* __restrict__ msum) {
    __shared__ int sh[256];
    int t = threadIdx.x;
    int v = (t < MSB) ? msum[t] : 0;
    sh[t] = v;
    __syncthreads();
    for (int off = 1; off < 256; off <<= 1) {
        int add = (t >= off) ? sh[t - off] : 0;
        __syncthreads();
        sh[t] += add;
        __syncthreads();
    }
    if (t < MSB) msum[t] = sh[t] - v;
}

__global__ void scan_m3(int* __restrict__ mat, const int* __restrict__ msum) {
    __shared__ int sh[256];
    int b = blockIdx.x, t = threadIdx.x;
    int i = b * 256 + t;
    int v = (i < MTOT) ? mat[i] : 0;
    sh[t] = v;
    __syncthreads();
    for (int off = 1; off < 256; off <<= 1) {
        int add = (t >= off) ? sh[t - off] : 0;
        __syncthreads();
        sh[t] += add;
        __syncthreads();
    }
    if (i < MTOT) mat[i] = sh[t] - v + msum[b];
}

__global__ void bucket_scatter(const int* __restrict__ ei, const int* __restrict__ mat,
                               unsigned int* __restrict__ part) {
    __shared__ int bas[NB];
    __shared__ int cur[NB];
    int blk = blockIdx.x, tid = threadIdx.x;
    for (int i = tid; i < NB; i += 256) { bas[i] = mat[i * PBLK + blk]; cur[i] = 0; }
    __syncthreads();
    int base = blk * ECH;
    for (int k = tid; k < ECH; k += 256) {
        int e = base + k;
        int r = ei[e];
        int c = ei[NE + e];
        int b = c >> 8;
        int local = atomicAdd(&cur[b], 1);
        part[bas[b] + local] = (unsigned)r | ((unsigned)(c & 255) << 24);
    }
}

__global__ void bucket_build(const unsigned int* __restrict__ part, const int* __restrict__ mat,
                             const float* __restrict__ x, int* __restrict__ csr_row,
                             int* __restrict__ ideg, int* __restrict__ offs,
                             float* __restrict__ dinv, float4* __restrict__ xpad,
                             uint4* __restrict__ xs) {
    __shared__ int lh[256];
    __shared__ int lex[256];
    __shared__ int cur[256];
    int b = blockIdx.x, tid = threadIdx.x;
    int ebase = mat[b * PBLK];
    int eend = (b == NB - 1) ? NE : mat[(b + 1) * PBLK];
    int m = eend - ebase;
    lh[tid] = 0;
    __syncthreads();
    for (int k = tid; k < m; k += 256) {
        unsigned v = part[ebase + k];
        atomicAdd(&lh[v >> 24], 1);
    }
    __syncthreads();
    int cnt = lh[tid];
    lex[tid] = cnt;
    __syncthreads();
    for (int off = 1; off < 256; off <<= 1) {
        int v = (tid >= off) ? lex[tid - off] : 0;
        __syncthreads();
        lex[tid] += v;
        __syncthreads();
    }
    int excl = lex[tid] - cnt;
    lex[tid] = excl;
    cur[tid] = 0;
    int n = b * 256 + tid;
    if (n < NN) {
        ideg[n] = cnt;
        offs[n] = ebase + excl;
        float di = rsqrtf((float)cnt + 1.0f);
        dinv[n] = di;
        float x0 = x[n * 3], x1 = x[n * 3 + 1], x2 = x[n * 3 + 2];
        xpad[n] = make_float4(x0, x1, x2, di);
        _Float16 hx = (_Float16)x0, hy = (_Float16)x1, hz = (_Float16)x2;
        half2v sx = {hx, hx}, sy = {hy, hy}, sz = {hz, hz};
        xs[n] = make_uint4(__builtin_bit_cast(unsigned int, sx),
                           __builtin_bit_cast(unsigned int, sy),
                           __builtin_bit_cast(unsigned int, sz), 0u);
    }
    if (b == 0 && tid == 0) offs[NN] = NE;
    __syncthreads();
    for (int k = tid; k < m; k += 256) {
        unsigned v = part[ebase + k];
        int cl = (int)(v >> 24);
        int r = (int)(v & 0x00FFFFFFu);
        int local = atomicAdd(&cur[cl], 1);
        csr_row[ebase + lex[cl] + local] = r;
    }
}

// Edge phase, packed fp16: 10 classes = 5 v_pk pairs per lane; half-wave 0
// takes even edges, half-wave 1 odd edges (interleaved). Broadcast via shfl
// of pre-packed splats xs[r]. fp16 pair-accumulators flushed to fp32 every 8.
__global__ __launch_bounds__(256, 6) void edgeconv_fused(
    const uint4* __restrict__ xs, const int* __restrict__ offs,
    const int* __restrict__ csr_row, const float* __restrict__ tab,
    _Float16* __restrict__ aggh) {
    int lane = threadIdx.x & 63;
    int j = lane & 31;
    int half = lane >> 5;

    half2v A0[5], A1[5], A2[5], B0[5], B1[5], B2[5], hb[5];
#pragma unroll
    for (int p = 0; p < 5; ++p) {
        int c0 = 2 * p, c1 = 2 * p + 1;
        A0[p] = half2v{(_Float16)tab[c0 * 96 + j],        (_Float16)tab[c1 * 96 + j]};
        A1[p] = half2v{(_Float16)tab[c0 * 96 + 32 + j],   (_Float16)tab[c1 * 96 + 32 + j]};
        A2[p] = half2v{(_Float16)tab[c0 * 96 + 64 + j],   (_Float16)tab[c1 * 96 + 64 + j]};
        B0[p] = half2v{(_Float16)tab[960 + c0 * 96 + j],      (_Float16)tab[960 + c1 * 96 + j]};
        B1[p] = half2v{(_Float16)tab[960 + c0 * 96 + 32 + j], (_Float16)tab[960 + c1 * 96 + 32 + j]};
        B2[p] = half2v{(_Float16)tab[960 + c0 * 96 + 64 + j], (_Float16)tab[960 + c1 * 96 + 64 + j]};
        hb[p] = half2v{(_Float16)tab[1920 + c0 * 32 + j], (_Float16)tab[1920 + c1 * 32 + j]};
    }
    const half2v zero = half2v{(_Float16)0.f, (_Float16)0.f};

    int wid = blockIdx.x * 4 + (threadIdx.x >> 6);
    const int wstride = gridDim.x * 4;

    for (int n = wid; n < NN; n += wstride) {
        uint4 qn = xs[n];
        half2v pxn = bch((int)qn.x), pyn = bch((int)qn.y), pzn = bch((int)qn.z);
        half2v va[5];
        float accf[10];
#pragma unroll
        for (int p = 0; p < 5; ++p) {
            va[p] = hb[p] + pxn * B0[p] + pyn * B1[p] + pzn * B2[p];
            accf[2 * p] = 0.f;
            accf[2 * p + 1] = 0.f;
        }
        int e0 = offs[n], e1 = offs[n + 1];
        for (int base = e0; base < e1; base += 64) {
            int ee = base + lane;
            int r = (ee < e1) ? csr_row[ee] : 0;
            uint4 q = xs[r];
            int cnt = e1 - base;
            if (cnt > 64) cnt = 64;
            int tfull = cnt >> 1;
            half2v acc[5];
#pragma unroll
            for (int p = 0; p < 5; ++p) acc[p] = zero;
            for (int t = 0; t < tfull; ++t) {
                int src = 2 * t + half;
                half2v px = bch(__shfl((int)q.x, src, 64));
                half2v py = bch(__shfl((int)q.y, src, 64));
                half2v pz = bch(__shfl((int)q.z, src, 64));
#pragma unroll
                for (int p = 0; p < 5; ++p) {
                    half2v u = va[p] + px * A0[p] + py * A1[p] + pz * A2[p];
                    u = __builtin_elementwise_max(u, zero);
                    acc[p] += u;
                }
                if ((t & 7) == 7) {
#pragma unroll
                    for (int p = 0; p < 5; ++p) {
                        accf[2 * p]     += (float)acc[p].x;
                        accf[2 * p + 1] += (float)acc[p].y;
                        acc[p] = zero;
                    }
                }
            }
            if (cnt & 1) {
                int src = cnt - 1;
                half2v px = bch(__shfl((int)q.x, src, 64));
                half2v py = bch(__shfl((int)q.y, src, 64));
                half2v pz = bch(__shfl((int)q.z, src, 64));
                if (half == 0) {
#pragma unroll
                    for (int p = 0; p < 5; ++p) {
                        half2v u = va[p] + px * A0[p] + py * A1[p] + pz * A2[p];
                        u = __builtin_elementwise_max(u, zero);
                        acc[p] += u;
                    }
                }
            }
#pragma unroll
            for (int p = 0; p < 5; ++p) {
                accf[2 * p]     += (float)acc[p].x;
                accf[2 * p + 1] += (float)acc[p].y;
            }
        }
        // cross-half reduce (half0 has even-edge sums, half1 odd-edge sums)
#pragma unroll
        for (int c = 0; c < 10; ++c) accf[c] += __shfl_xor(accf[c], 32, 64);
        _Float16* arow = aggh + (size_t)n * 320 + j;
#pragma unroll
        for (int i = 0; i < 5; ++i) {
            int c = half * 5 + i;
            arow[c * 32] = (_Float16)accf[c];
        }
    }
}

// Fold via MFMA (plain fp16, 2 MFMA/kc) + fused xw1-init; writes y1 = h*dinv fp16.
__global__ __launch_bounds__(256) void fold_mfma(
    const _Float16* __restrict__ aggh, const _Float16* __restrict__ MfragG,
    const float4* __restrict__ xpad, const int* __restrict__ ideg,
    const float* __restrict__ tab, const float* __restrict__ g1W,
    _Float16* __restrict__ y1) {
    __shared__ _Float16 Mf[10240];
    {
        const uint4* src = (const uint4*)MfragG;
        uint4* dst = (uint4*)Mf;
        for (int i = threadIdx.x; i < 1280; i += 256) dst[i] = src[i];
    }
    __syncthreads();

    int wave = blockIdx.x * 4 + (threadIdx.x >> 6);
    int lane = threadIdx.x & 63;
    int n0 = wave * 16;
    if (n0 >= NN) return;

    int m = lane & 15, q = lane >> 4;
    int arow_n = n0 + m;
    bool rowok = arow_n < NN;
    const _Float16* arow = aggh + (size_t)arow_n * 320 + q * 8;

    const half8* mf = (const half8*)Mf;
    f32x4 acc0 = {0.f, 0.f, 0.f, 0.f};
    f32x4 acc1 = {0.f, 0.f, 0.f, 0.f};

    for (int kc = 0; kc < 10; ++kc) {
        half8 a;
        if (rowok) a = *(const half8*)(arow + kc * 32);
        else {
#pragma unroll
            for (int i = 0; i < 8; ++i) a[i] = (_Float16)0.f;
        }
        half8 b0 = mf[(kc * 2 + 0) * 64 + lane];
        half8 b1 = mf[(kc * 2 + 1) * 64 + lane];
        acc0 = __builtin_amdgcn_mfma_f32_16x16x32_f16(a, b0, acc0, 0, 0, 0);
        acc1 = __builtin_amdgcn_mfma_f32_16x16x32_f16(a, b1, acc1, 0, 0, 0);
    }

    int jcol = lane & 15;
    float t0 = tab[12480 + jcol],      t1 = tab[12480 + 16 + jcol];
    float w00 = g1W[jcol],      w01 = g1W[32 + jcol],      w02 = g1W[64 + jcol];
    float w10 = g1W[16 + jcol], w11 = g1W[48 + jcol],      w12 = g1W[80 + jcol];
#pragma unroll
    for (int r = 0; r < 4; ++r) {
        int node = n0 + q * 4 + r;
        if (node < NN) {
            float4 xn = xpad[node];
            float dg = (float)ideg[node];
            float v0 = dg * t0 + xn.x * w00 + xn.y * w01 + xn.z * w02 + acc0[r];
            float v1 = dg * t1 + xn.x * w10 + xn.y * w11 + xn.z * w12 + acc1[r];
            y1[node * 32 + jcol]      = (_Float16)(v0 * xn.w);
            y1[node * 32 + 16 + jcol] = (_Float16)(v1 * xn.w);
        }
    }
}

// prop1 + fused xw2: 4 nodes/wave, 16 lanes/node, unroll-8 gathers.
__global__ __launch_bounds__(256, 8) void prop1_fused(
    const int* __restrict__ offs, const int* __restrict__ csr_row,
    const unsigned int* __restrict__ y1p, const float* __restrict__ dinv,
    const float* __restrict__ g1b, const float* __restrict__ g2W,
    unsigned int* __restrict__ y2p) {
    __shared__ float g2s[1024];
    for (int i = threadIdx.x; i < 1024; i += 256) g2s[i] = g2W[i];
    __syncthreads();

    int lane = threadIdx.x & 63;
    int l = lane & 15;
    int wid = blockIdx.x * 4 + (threadIdx.x >> 6);
    int n = wid * 4 + (lane >> 4);
    if (n >= NN) return;

    int e0 = offs[n], e1 = offs[n + 1];
    float sAl = 0.f, sAh = 0.f, sBl = 0.f, sBh = 0.f;
    int e = e0;
    for (; e + 7 < e1; e += 8) {
        int r[8];
#pragma unroll
        for (int u = 0; u < 8; ++u) r[u] = csr_row[e + u];
        half2v p[8];
#pragma unroll
        for (int u = 0; u < 8; ++u) p[u] = __builtin_bit_cast(half2v, y1p[r[u] * 16 + l]);
#pragma unroll
        for (int u = 0; u < 8; u += 2) {
            sAl += (float)p[u].x;     sAh += (float)p[u].y;
            sBl += (float)p[u + 1].x; sBh += (float)p[u + 1].y;
        }
    }
    for (; e < e1; ++e) {
        int r = csr_row[e];
        half2v p = __builtin_bit_cast(half2v, y1p[r * 16 + l]);
        sAl += (float)p.x; sAh += (float)p.y;
    }
    float di = dinv[n];
    half2v pn = __builtin_bit_cast(half2v, y1p[n * 16 + l]);
    float h1l = di * (sAl + sBl + (float)pn.x);
    float h1h = di * (sAh + sBh + (float)pn.y);
    float hl = fmaxf(h1l + g1b[2 * l], 0.f);
    float hh = fmaxf(h1h + g1b[2 * l + 1], 0.f);

    float al = 0.f, ah = 0.f;
    int base = lane & 48;
#pragma unroll
    for (int m = 0; m < 16; ++m) {
        float xl = __shfl(hl, base + m, 64);
        float xh2 = __shfl(hh, base + m, 64);
        al += xl * g2s[(2 * m) * 32 + 2 * l] + xh2 * g2s[(2 * m + 1) * 32 + 2 * l];
        ah += xl * g2s[(2 * m) * 32 + 2 * l + 1] + xh2 * g2s[(2 * m + 1) * 32 + 2 * l + 1];
    }
    half2v o = {(_Float16)(al * di), (_Float16)(ah * di)};
    y2p[n * 16 + l] = __builtin_bit_cast(unsigned int, o);
}

// prop2: same structure; h2 = di*(sum y2[r] + y2[n]); stored fp16 (pre-bias).
__global__ __launch_bounds__(256, 8) void prop2_plain(
    const int* __restrict__ offs, const int* __restrict__ csr_row,
    const unsigned int* __restrict__ y2p, const float* __restrict__ dinv,
    unsigned int* __restrict__ outp) {
    int lane = threadIdx.x & 63;
    int l = lane & 15;
    int wid = blockIdx.x * 4 + (threadIdx.x >> 6);
    int n = wid * 4 + (lane >> 4);
    if (n >= NN) return;

    int e0 = offs[n], e1 = offs[n + 1];
    float sAl = 0.f, sAh = 0.f, sBl = 0.f, sBh = 0.f;
    int e = e0;
    for (; e + 7 < e1; e += 8) {
        int r[8];
#pragma unroll
        for (int u = 0; u < 8; ++u) r[u] = csr_row[e + u];
        half2v p[8];
#pragma unroll
        for (int u = 0; u < 8; ++u) p[u] = __builtin_bit_cast(half2v, y2p[r[u] * 16 + l]);
#pragma unroll
        for (int u = 0; u < 8; u += 2) {
            sAl += (float)p[u].x;     sAh += (float)p[u].y;
            sBl += (float)p[u + 1].x; sBh += (float)p[u + 1].y;
        }
    }
    for (; e < e1; ++e) {
        int r = csr_row[e];
        half2v p = __builtin_bit_cast(half2v, y2p[r * 16 + l]);
        sAl += (float)p.x; sAh += (float)p.y;
    }
    float di = dinv[n];
    half2v pn = __builtin_bit_cast(half2v, y2p[n * 16 + l]);
    half2v o = {(_Float16)(di * (sAl + sBl + (float)pn.x)),
                (_Float16)(di * (sAh + sBh + (float)pn.y))};
    outp[n * 16 + l] = __builtin_bit_cast(unsigned int, o);
}

__global__ void pool_seg(const _Float16* __restrict__ h2, const float* __restrict__ g2b,
                         const int* __restrict__ batch, float* __restrict__ pooled,
                         float* __restrict__ counts) {
    int grp = threadIdx.x >> 5, j = threadIdx.x & 31;
    int base = (blockIdx.x * 8 + grp) * 64;
    if (base >= NN) return;
    float bj = g2b[j];
    float acc = 0.f, cnt = 0.f;
    int curg = -1;
    int lim = base + 64;
    if (lim > NN) lim = NN;
    for (int n = base; n < lim; ++n) {
        int g = batch[n];
        if (g != curg) {
            if (curg >= 0) {
                atomicAdd(&pooled[curg * 32 + j], acc);
                if (j == 0) atomicAdd(&counts[curg], cnt);
            }
            curg = g; acc = 0.f; cnt = 0.f;
        }
        acc += fmaxf((float)h2[n * 32 + j] + bj, 0.f);
        cnt += 1.f;
    }
    if (curg >= 0) {
        atomicAdd(&pooled[curg * 32 + j], acc);
        if (j == 0) atomicAdd(&counts[curg], cnt);
    }
}

__global__ void final_kernel(const float* __restrict__ pooled, const float* __restrict__ counts,
                             const float* __restrict__ clsW, const float* __restrict__ clsb,
                             float* __restrict__ out) {
    int tid = threadIdx.x;
    if (tid >= GG * CC) return;
    int g = tid / CC, cc = tid % CC;
    float inv = 1.0f / fmaxf(counts[g], 1.0f);
    float s = clsb[cc];
    for (int j = 0; j < 32; ++j) s += (pooled[g * 32 + j] * inv) * clsW[j * CC + cc];
    out[g * CC + cc] = s;
}

extern "C" void kernel_launch(void* const* d_in, const int* in_sizes, int n_in,
                              void* d_out, int out_size, void* d_ws, size_t ws_size,
                              hipStream_t stream) {
    const float* x     = (const float*)d_in[0];
    const int*   ei    = (const int*)d_in[1];
    const int*   batch = (const int*)d_in[2];
    const float* fW    = (const float*)d_in[3];
    const float* fb    = (const float*)d_in[4];
    const float* W1    = (const float*)d_in[5];
    const float* b1    = (const float*)d_in[6];
    const float* W2    = (const float*)d_in[7];
    const float* b2    = (const float*)d_in[8];
    const float* g1W   = (const float*)d_in[9];
    const float* g1b   = (const float*)d_in[10];
    const float* g2W   = (const float*)d_in[11];
    const float* g2b   = (const float*)d_in[12];
    const float* clsW  = (const float*)d_in[13];
    const float* clsb  = (const float*)d_in[14];
    float* out = (float*)d_out;

    float4*         xpad    = (float4*)d_ws;                          // 1.6 MB
    uint4*          xs      = (uint4*)(xpad + NN);                    // 1.6 MB (fp16 splats)
    _Float16*       aggh    = (_Float16*)(xs + NN);                   // 64 MB (full)
    unsigned int*   part    = (unsigned int*)aggh;                    // ALIAS: build-phase only
    int*            csr_row = (int*)(aggh + (size_t)NN * 320);        // 6.4 MB
    int*            mat     = (int*)(csr_row + NE);
    int*            msum    = mat + MTOT;
    int*            ideg    = msum + 256;
    int*            offs    = ideg + NN;
    float*          dinv    = (float*)(offs + NN + 1);
    float*          tab     = dinv + NN;
    _Float16*       Mfrag   = (_Float16*)(tab + 16384);               // 20 KB
    _Float16*       y1      = Mfrag + 10240;                          // 6.4 MB
    unsigned int*   y2p     = (unsigned int*)(y1 + (size_t)NN * 32);  // 6.4 MB
    unsigned int*   h2p     = y2p + (size_t)NN * 16;                  // 6.4 MB
    float*          pooled  = (float*)(h2p + (size_t)NN * 16);
    float*          counts  = pooled + GG * 32;

    const int propBlocks = (NN + 15) / 16;
    const int foldBlocks = ((NN + 15) / 16 + 3) / 4;

    zero_f<<<(GG * 33 + 255) / 256, 256, 0, stream>>>(pooled, GG * 33);
    precompute_small<<<10, 1024, 0, stream>>>(fW, fb, W1, b1, W2, b2, g1W, tab);
    mfrag_kernel<<<5, 256, 0, stream>>>(tab, Mfrag);

    bucket_hist<<<PBLK, 256, 0, stream>>>(ei, mat);
    scan_m1<<<MSB, 256, 0, stream>>>(mat, msum);
    scan_m2<<<1, 256, 0, stream>>>(msum);
    scan_m3<<<MSB, 256, 0, stream>>>(mat, msum);
    bucket_scatter<<<PBLK, 256, 0, stream>>>(ei, mat, part);
    bucket_build<<<NB, 256, 0, stream>>>(part, mat, x, csr_row, ideg, offs, dinv, xpad, xs);

    edgeconv_fused<<<2048, 256, 0, stream>>>(xs, offs, csr_row, tab, aggh);
    fold_mfma<<<foldBlocks, 256, 0, stream>>>(aggh, Mfrag, xpad, ideg, tab, g1W, y1);

    prop1_fused<<<propBlocks, 256, 0, stream>>>(offs, csr_row, (const unsigned int*)y1,
                                                dinv, g1b, g2W, y2p);
    prop2_plain<<<propBlocks, 256, 0, stream>>>(offs, csr_row, y2p, dinv, h2p);
    pool_seg<<<(NN + 511) / 512, 256, 0, stream>>>((const _Float16*)h2p, g2b, batch,
                                                   pooled, counts);
    final_kernel<<<1, 640, 0, stream>>>(pooled, counts, clsW, clsb, out);
}